// Round 1
// baseline (694.867 us; speedup 1.0000x reference)
//
#include <hip/hip_runtime.h>

// ---------------- problem constants ----------------
constexpr int CB   = 4;
constexpr int CS   = 1024;
constexpr int CD   = 1024;
constexpr int CH   = 16;
constexpr int CDH  = 64;
constexpr int CDFF = 4096;
constexpr int CNT  = CB * CS;   // 4096 tokens

typedef unsigned short ush;
typedef __bf16 bf16_t;
typedef bf16_t bf16x8 __attribute__((ext_vector_type(8)));
typedef float  f32x4  __attribute__((ext_vector_type(4)));

__device__ __forceinline__ ush f2bf(float f) {
    union { float f; unsigned u; } v; v.f = f;
    unsigned u = v.u;
    unsigned r = (u + 0x7fffu + ((u >> 16) & 1u)) >> 16;
    return (ush)r;
}

// ---------------- conversions ----------------
__global__ __launch_bounds__(256) void k_f32_to_bf16(const float* __restrict__ in,
                                                     ush* __restrict__ out, int n) {
    int i = blockIdx.x * 256 + threadIdx.x;
    int stride = gridDim.x * 256;
    for (; i < n; i += stride) out[i] = f2bf(in[i]);
}

__global__ __launch_bounds__(256) void k_zero(float* __restrict__ p, int n) {
    int i = blockIdx.x * 256 + threadIdx.x;
    int stride = gridDim.x * 256;
    for (; i < n; i += stride) p[i] = 0.f;
}

// ---------------- bf16 MFMA GEMM: C[M,N] = A[M,K] * B[N,K]^T ----------------
// EPI: 0 = plain f32 out, 1 = +bias f32 out, 3 = +bias, relu, bf16 out
template <int EPI>
__global__ __launch_bounds__(256) void k_gemm_bt(const ush* __restrict__ A,
                                                 const ush* __restrict__ Bm,
                                                 float* __restrict__ C,
                                                 ush* __restrict__ Cb,
                                                 const float* __restrict__ bias,
                                                 int N, int K) {
    __shared__ ush As[128][40];   // 32 k + 8 pad (bank-conflict-free frag reads)
    __shared__ ush Bs[128][40];
    const int tid  = threadIdx.x;
    const int wave = tid >> 6, lane = tid & 63;
    const int quad = lane >> 4, r = lane & 15;
    const int wm = wave >> 1, wn = wave & 1;
    const int bm = blockIdx.x, bn = blockIdx.y;

    const int srow = tid >> 1;
    const int scol = (tid & 1) * 16;
    const ush* aptr = A  + (size_t)(bm * 128 + srow) * K + scol;
    const ush* bptr = Bm + (size_t)(bn * 128 + srow) * K + scol;

    f32x4 acc[4][4];
#pragma unroll
    for (int i = 0; i < 4; i++)
#pragma unroll
        for (int j = 0; j < 4; j++) acc[i][j] = (f32x4){0.f, 0.f, 0.f, 0.f};

    for (int k0 = 0; k0 < K; k0 += 32) {
        uint4 a0 = *(const uint4*)(aptr);
        uint4 a1 = *(const uint4*)(aptr + 8);
        uint4 b0 = *(const uint4*)(bptr);
        uint4 b1 = *(const uint4*)(bptr + 8);
        *(uint4*)&As[srow][scol]     = a0;
        *(uint4*)&As[srow][scol + 8] = a1;
        *(uint4*)&Bs[srow][scol]     = b0;
        *(uint4*)&Bs[srow][scol + 8] = b1;
        aptr += 32; bptr += 32;
        __syncthreads();
        bf16x8 af[4], bfr[4];
#pragma unroll
        for (int i = 0; i < 4; i++) {
            af[i]  = *(const bf16x8*)&As[wm * 64 + i * 16 + r][quad * 8];
            bfr[i] = *(const bf16x8*)&Bs[wn * 64 + i * 16 + r][quad * 8];
        }
#pragma unroll
        for (int i = 0; i < 4; i++)
#pragma unroll
            for (int j = 0; j < 4; j++)
                acc[i][j] = __builtin_amdgcn_mfma_f32_16x16x32_bf16(af[i], bfr[j], acc[i][j], 0, 0, 0);
        __syncthreads();
    }

#pragma unroll
    for (int i = 0; i < 4; i++) {
        const int row0 = bm * 128 + wm * 64 + i * 16 + quad * 4;
#pragma unroll
        for (int j = 0; j < 4; j++) {
            const int col = bn * 128 + wn * 64 + j * 16 + r;
            float bv = (EPI >= 1) ? bias[col] : 0.f;
#pragma unroll
            for (int g = 0; g < 4; g++) {
                float v = acc[i][j][g] + bv;
                size_t off = (size_t)(row0 + g) * N + col;
                if (EPI == 3) { v = fmaxf(v, 0.f); Cb[off] = f2bf(v); }
                else          { C[off] = v; }
            }
        }
    }
}

// ---------------- per-head layernorm (over DH=64) ----------------
__global__ __launch_bounds__(256) void k_ln_head(const float* __restrict__ in,
                                                 const float* __restrict__ gam,
                                                 const float* __restrict__ bet,
                                                 ush* __restrict__ outb,
                                                 float* __restrict__ outf) {
    const int lane = threadIdx.x & 63;
    const int gid  = blockIdx.x * 4 + (threadIdx.x >> 6);
    const size_t base = (size_t)gid * 64;
    float x = in[base + lane];
    float s = x, q = x * x;
#pragma unroll
    for (int off = 32; off >= 1; off >>= 1) {
        s += __shfl_xor(s, off);
        q += __shfl_xor(q, off);
    }
    float mu  = s * (1.f / 64.f);
    float var = q * (1.f / 64.f) - mu * mu;
    float y = (x - mu) * rsqrtf(var + 1e-5f) * gam[lane] + bet[lane];
    if (outb) outb[base + lane] = f2bf(y);
    if (outf) outf[base + lane] = y;
}

// ---------------- attention column-sum kernel ----------------
// w_col[b,h,l] = sum_q softmax_row_q(pre)[l]   (excluding all-masked rows; those
// contribute exactly uniform 1/1024, added later in k_scale_v)
__global__ __launch_bounds__(256) void k_attn(const ush* __restrict__ qb,
                                              const ush* __restrict__ kb,
                                              const float* __restrict__ mask,
                                              float* __restrict__ wcol) {
    __shared__ ush   Qs[64][72];
    __shared__ ush   Ks[128][72];
    __shared__ float maskL[CS];
    __shared__ float row_rs[64];
    __shared__ float colpart[4][128];

    const int tid  = threadIdx.x;
    const int wave = tid >> 6, lane = tid & 63;
    const int quad = lane >> 4, r = lane & 15;
    const int bh = blockIdx.x;
    const int bi = bh >> 4, hi = bh & 15;
    const int q0 = blockIdx.y * 64;

    for (int i = tid; i < CS; i += 256) maskL[i] = mask[bi * CS + i];
    {
        int row = tid >> 2, seg = (tid & 3) * 16;
        const ush* src = qb + ((size_t)(bi * CS + q0 + row) * CD + hi * 64 + seg);
        uint4 v0 = *(const uint4*)src;
        uint4 v1 = *(const uint4*)(src + 8);
        *(uint4*)&Qs[row][seg]     = v0;
        *(uint4*)&Qs[row][seg + 8] = v1;
    }
    __syncthreads();

    bf16x8 af0 = *(const bf16x8*)&Qs[wave * 16 + r][quad * 8];
    bf16x8 af1 = *(const bf16x8*)&Qs[wave * 16 + r][32 + quad * 8];

    auto stageK = [&](int l0) {
        int row = tid >> 1, seg = (tid & 1) * 32;
        const ush* src = kb + ((size_t)(bi * CS + l0 + row) * CD + hi * 64 + seg);
        uint4 v0 = *(const uint4*)src;
        uint4 v1 = *(const uint4*)(src + 8);
        uint4 v2 = *(const uint4*)(src + 16);
        uint4 v3 = *(const uint4*)(src + 24);
        *(uint4*)&Ks[row][seg]      = v0;
        *(uint4*)&Ks[row][seg + 8]  = v1;
        *(uint4*)&Ks[row][seg + 16] = v2;
        *(uint4*)&Ks[row][seg + 24] = v3;
    };

    // ---- phase 1: row sums of exp(pre - 8) ----
    float s_loc[4] = {0.f, 0.f, 0.f, 0.f};
    for (int l0 = 0; l0 < CS; l0 += 128) {
        __syncthreads();
        stageK(l0);
        __syncthreads();
#pragma unroll
        for (int jt = 0; jt < 8; jt++) {
            bf16x8 bf0 = *(const bf16x8*)&Ks[jt * 16 + r][quad * 8];
            bf16x8 bf1 = *(const bf16x8*)&Ks[jt * 16 + r][32 + quad * 8];
            f32x4 sc = (f32x4){0.f, 0.f, 0.f, 0.f};
            sc = __builtin_amdgcn_mfma_f32_16x16x32_bf16(af0, bf0, sc, 0, 0, 0);
            sc = __builtin_amdgcn_mfma_f32_16x16x32_bf16(af1, bf1, sc, 0, 0, 0);
            const int l = l0 + jt * 16 + r;
            const float ml = maskL[l];
#pragma unroll
            for (int g = 0; g < 4; g++) {
                const int qg = q0 + wave * 16 + quad * 4 + g;
                float e  = sc[g] * 0.03125f;
                float mv = (qg > l) ? 0.f : maskL[qg] * ml * (-1e20f);
                float pre = e + mv - fabsf((float)(qg - l));
                s_loc[g] += expf(pre - 8.f);
            }
        }
    }
#pragma unroll
    for (int g = 0; g < 4; g++) {
        float s = s_loc[g];
        s += __shfl_xor(s, 1); s += __shfl_xor(s, 2);
        s += __shfl_xor(s, 4); s += __shfl_xor(s, 8);
        if (r == 0) row_rs[wave * 16 + quad * 4 + g] = (s > 0.f) ? 1.f / s : 0.f;
    }
    __syncthreads();
    float rs[4];
#pragma unroll
    for (int g = 0; g < 4; g++) rs[g] = row_rs[wave * 16 + quad * 4 + g];

    // ---- phase 2: accumulate column sums of normalized probs ----
    for (int l0 = 0; l0 < CS; l0 += 128) {
        __syncthreads();
        stageK(l0);
        __syncthreads();
#pragma unroll
        for (int jt = 0; jt < 8; jt++) {
            bf16x8 bf0 = *(const bf16x8*)&Ks[jt * 16 + r][quad * 8];
            bf16x8 bf1 = *(const bf16x8*)&Ks[jt * 16 + r][32 + quad * 8];
            f32x4 sc = (f32x4){0.f, 0.f, 0.f, 0.f};
            sc = __builtin_amdgcn_mfma_f32_16x16x32_bf16(af0, bf0, sc, 0, 0, 0);
            sc = __builtin_amdgcn_mfma_f32_16x16x32_bf16(af1, bf1, sc, 0, 0, 0);
            const int l = l0 + jt * 16 + r;
            const float ml = maskL[l];
            float csum = 0.f;
#pragma unroll
            for (int g = 0; g < 4; g++) {
                const int qg = q0 + wave * 16 + quad * 4 + g;
                float e  = sc[g] * 0.03125f;
                float mv = (qg > l) ? 0.f : maskL[qg] * ml * (-1e20f);
                float pre = e + mv - fabsf((float)(qg - l));
                csum += expf(pre - 8.f) * rs[g];
            }
            csum += __shfl_xor(csum, 16);
            csum += __shfl_xor(csum, 32);
            if (quad == 0) colpart[wave][jt * 16 + r] = csum;
        }
        __syncthreads();
        if (tid < 128) {
            float v = colpart[0][tid] + colpart[1][tid] + colpart[2][tid] + colpart[3][tid];
            atomicAdd(&wcol[(size_t)bh * CS + l0 + tid], v);
        }
    }
}

// ---------------- scale v by column weights (+ uniform row-0 term) ----------------
__global__ __launch_bounds__(256) void k_scale_v(const float* __restrict__ vin,
                                                 const float* __restrict__ wcol,
                                                 ush* __restrict__ out) {
    int i = blockIdx.x * 256 + threadIdx.x;
    int stride = gridDim.x * 256;
    for (; i < CNT * CD; i += stride) {
        int token = i >> 10;            // D = 1024
        int l = token & (CS - 1);
        int b = token >> 10;            // S = 1024
        int h = (i & (CD - 1)) >> 6;    // DH = 64
        float w = wcol[(size_t)(b * CH + h) * CS + l] + (1.f / 1024.f);
        out[i] = f2bf(w * vin[i]);
    }
}

// ---------------- row layernorm over D=1024, fused variants ----------------
// MODE 0: LN(in0) -> bf16 out
// MODE 1: LN(in0) -> f32 out (in-place safe)
// MODE 2: f = sigmoid(in0+in1+bvec); t = f*in0+(1-f)*in1; LN(t) -> f32 + bf16
// MODE 3: LN(in0+in1) -> f32 out
template <int MODE>
__global__ __launch_bounds__(256) void k_ln_row(const float* __restrict__ in0,
                                                const float* __restrict__ in1,
                                                const float* __restrict__ bvec,
                                                const float* __restrict__ gam,
                                                const float* __restrict__ bet,
                                                float* __restrict__ outf,
                                                ush* __restrict__ outb) {
    __shared__ float red[2][4];
    const int tid = threadIdx.x, wave = tid >> 6, lane = tid & 63;
    const size_t base = (size_t)blockIdx.x * CD;
    float t[4];
#pragma unroll
    for (int j = 0; j < 4; j++) {
        int col = tid + j * 256;
        if (MODE == 2) {
            float a = in0[base + col], c = in1[base + col];
            float f = 1.f / (1.f + expf(-(a + c + bvec[col])));
            t[j] = f * a + (1.f - f) * c;
        } else if (MODE == 3) {
            t[j] = in0[base + col] + in1[base + col];
        } else {
            t[j] = in0[base + col];
        }
    }
    float s = 0.f, q = 0.f;
#pragma unroll
    for (int j = 0; j < 4; j++) { s += t[j]; q += t[j] * t[j]; }
#pragma unroll
    for (int off = 32; off >= 1; off >>= 1) {
        s += __shfl_xor(s, off);
        q += __shfl_xor(q, off);
    }
    if (lane == 0) { red[0][wave] = s; red[1][wave] = q; }
    __syncthreads();
    s = red[0][0] + red[0][1] + red[0][2] + red[0][3];
    q = red[1][0] + red[1][1] + red[1][2] + red[1][3];
    float mu = s * (1.f / 1024.f);
    float rstd = rsqrtf(q * (1.f / 1024.f) - mu * mu + 1e-5f);
#pragma unroll
    for (int j = 0; j < 4; j++) {
        int col = tid + j * 256;
        float y = (t[j] - mu) * rstd * gam[col] + bet[col];
        if (MODE == 0)      outb[base + col] = f2bf(y);
        else if (MODE == 1) outf[base + col] = y;
        else if (MODE == 2) { outf[base + col] = y; outb[base + col] = f2bf(y); }
        else                outf[base + col] = y;
    }
}

// ---------------- host launch ----------------
extern "C" void kernel_launch(void* const* d_in, const int* in_sizes, int n_in,
                              void* d_out, int out_size, void* d_ws, size_t ws_size,
                              hipStream_t stream) {
    const float* x    = (const float*)d_in[0];
    const float* mask = (const float*)d_in[1];
    const float* Wq   = (const float*)d_in[2];
    const float* Wk   = (const float*)d_in[3];
    const float* Wv   = (const float*)d_in[4];
    const float* ln1g = (const float*)d_in[5];
    const float* ln1b = (const float*)d_in[6];
    const float* Wo   = (const float*)d_in[7];
    const float* bo   = (const float*)d_in[8];
    const float* ln2g = (const float*)d_in[9];
    const float* ln2b = (const float*)d_in[10];
    const float* Ws   = (const float*)d_in[11];
    const float* Wh   = (const float*)d_in[12];
    const float* bf_  = (const float*)d_in[13];
    const float* lnfgg = (const float*)d_in[14];
    const float* lnfgb = (const float*)d_in[15];
    const float* Wp1  = (const float*)d_in[16];
    const float* bp1  = (const float*)d_in[17];
    const float* Wp2  = (const float*)d_in[18];
    const float* bp2  = (const float*)d_in[19];
    const float* lnffg = (const float*)d_in[20];
    const float* lnffb = (const float*)d_in[21];
    float* out = (float*)d_out;

    char* p = (char*)d_ws;
    auto alloc = [&](size_t bytes) -> char* {
        char* r = p;
        p += (bytes + 255) & ~(size_t)255;
        return r;
    };
    ush* xb    = (ush*)alloc((size_t)CNT * CD * 2);
    ush* Wqb   = (ush*)alloc((size_t)CD * CD * 2);
    ush* Wkb   = (ush*)alloc((size_t)CD * CD * 2);
    ush* Wvb   = (ush*)alloc((size_t)CD * CD * 2);
    ush* Wob   = (ush*)alloc((size_t)CD * CD * 2);
    ush* Wsb   = (ush*)alloc((size_t)CD * CD * 2);
    ush* Whb   = (ush*)alloc((size_t)CD * CD * 2);
    ush* Wp1b  = (ush*)alloc((size_t)CDFF * CD * 2);
    ush* Wp2b  = (ush*)alloc((size_t)CD * CDFF * 2);
    float* bufQ = (float*)alloc((size_t)CNT * CD * 4);
    float* bufK = (float*)alloc((size_t)CNT * CD * 4);
    float* bufV = (float*)alloc((size_t)CNT * CD * 4);
    float* bufG = (float*)alloc((size_t)CNT * CD * 4);
    ush* qlnb  = (ush*)alloc((size_t)CNT * CD * 2);
    ush* klnb  = (ush*)alloc((size_t)CNT * CD * 2);
    ush* gb    = (ush*)alloc((size_t)CNT * CD * 2);
    ush* ff1b  = (ush*)alloc((size_t)CNT * CDFF * 2);
    float* wcol = (float*)alloc((size_t)CB * CH * CS * 4);
    ush* attb = qlnb;  // alias: q_ln consumed before scale_v writes
    ush* hb   = klnb;  // alias: k_ln consumed before ln_row<0> writes

    dim3 blk(256);

    // bf16 conversions
    k_f32_to_bf16<<<dim3(4096), blk, 0, stream>>>(x, xb, CNT * CD);
    k_f32_to_bf16<<<dim3(1024), blk, 0, stream>>>(Wq, Wqb, CD * CD);
    k_f32_to_bf16<<<dim3(1024), blk, 0, stream>>>(Wk, Wkb, CD * CD);
    k_f32_to_bf16<<<dim3(1024), blk, 0, stream>>>(Wv, Wvb, CD * CD);
    k_f32_to_bf16<<<dim3(1024), blk, 0, stream>>>(Wo, Wob, CD * CD);
    k_f32_to_bf16<<<dim3(1024), blk, 0, stream>>>(Ws, Wsb, CD * CD);
    k_f32_to_bf16<<<dim3(1024), blk, 0, stream>>>(Wh, Whb, CD * CD);
    k_f32_to_bf16<<<dim3(4096), blk, 0, stream>>>(Wp1, Wp1b, CDFF * CD);
    k_f32_to_bf16<<<dim3(4096), blk, 0, stream>>>(Wp2, Wp2b, CD * CDFF);

    dim3 gD(CNT / 128, CD / 128);     // 32 x 8
    dim3 gF(CNT / 128, CDFF / 128);   // 32 x 32

    // QKV projections
    k_gemm_bt<0><<<gD, blk, 0, stream>>>(xb, Wqb, bufQ, nullptr, nullptr, CD, CD);
    k_gemm_bt<0><<<gD, blk, 0, stream>>>(xb, Wkb, bufK, nullptr, nullptr, CD, CD);
    k_gemm_bt<0><<<gD, blk, 0, stream>>>(xb, Wvb, bufV, nullptr, nullptr, CD, CD);

    // per-head LN
    k_ln_head<<<dim3(CNT * CH / 4), blk, 0, stream>>>(bufQ, ln1g, ln1b, qlnb, nullptr);
    k_ln_head<<<dim3(CNT * CH / 4), blk, 0, stream>>>(bufK, ln1g, ln1b, klnb, nullptr);
    k_ln_head<<<dim3(CNT * CH / 4), blk, 0, stream>>>(bufV, ln1g, ln1b, nullptr, bufV);

    // attention column sums
    k_zero<<<dim3(64), blk, 0, stream>>>(wcol, CB * CH * CS);
    k_attn<<<dim3(CB * CH, CS / 64), blk, 0, stream>>>(qlnb, klnb, mask, wcol);
    k_scale_v<<<dim3(4096), blk, 0, stream>>>(bufV, wcol, attb);

    // output projection + LN2
    k_gemm_bt<1><<<gD, blk, 0, stream>>>(attb, Wob, bufQ, nullptr, bo, CD, CD);
    k_ln_row<0><<<dim3(CNT), blk, 0, stream>>>(bufQ, nullptr, nullptr, ln2g, ln2b, nullptr, hb);

    // fusion gate
    k_gemm_bt<0><<<gD, blk, 0, stream>>>(xb, Wsb, bufK, nullptr, nullptr, CD, CD);
    k_gemm_bt<0><<<gD, blk, 0, stream>>>(hb, Whb, bufV, nullptr, nullptr, CD, CD);
    k_ln_row<1><<<dim3(CNT), blk, 0, stream>>>(bufK, nullptr, nullptr, lnfgg, lnfgb, bufK, nullptr);
    k_ln_row<1><<<dim3(CNT), blk, 0, stream>>>(bufV, nullptr, nullptr, lnfgg, lnfgb, bufV, nullptr);
    k_ln_row<2><<<dim3(CNT), blk, 0, stream>>>(bufK, bufV, bf_, lnfgg, lnfgb, bufG, gb);

    // FFN + residual + final LN
    k_gemm_bt<3><<<gF, blk, 0, stream>>>(gb, Wp1b, nullptr, ff1b, bp1, CDFF, CD);
    k_gemm_bt<1><<<gD, blk, 0, stream>>>(ff1b, Wp2b, bufQ, nullptr, bp2, CD, CDFF);
    k_ln_row<3><<<dim3(CNT), blk, 0, stream>>>(bufQ, bufG, nullptr, lnffg, lnffb, out, nullptr);

    (void)in_sizes; (void)n_in; (void)out_size; (void)ws_size;
}

// Round 2
// 461.862 us; speedup vs baseline: 1.5045x; 1.5045x over previous
//
#include <hip/hip_runtime.h>

// ---------------- problem constants ----------------
constexpr int CB   = 4;
constexpr int CS   = 1024;
constexpr int CD   = 1024;
constexpr int CH   = 16;
constexpr int CDFF = 4096;
constexpr int CNT  = CB * CS;   // 4096 tokens

typedef unsigned short ush;
typedef __bf16 bf16_t;
typedef bf16_t bf16x8 __attribute__((ext_vector_type(8)));
typedef float  f32x4  __attribute__((ext_vector_type(4)));

__device__ __forceinline__ ush f2bf(float f) {
    union { float f; unsigned u; } v; v.f = f;
    unsigned u = v.u;
    return (ush)((u + 0x7fffu + ((u >> 16) & 1u)) >> 16);
}

// async global->LDS, 16B per lane (dest = wave-uniform base + lane*16)
__device__ __forceinline__ void gll16(const void* g, void* l) {
    __builtin_amdgcn_global_load_lds((const __attribute__((address_space(1))) void*)g,
                                     (__attribute__((address_space(3))) void*)l,
                                     16, 0, 0);
}

// ---------------- fused conversions (x + all weights) ----------------
// arena layout (elements): [Wq 1M | Wk 1M | Wv 1M | Wo 1M | Ws 1M | Wh 1M | Wp1 4M | Wp2 4M]
constexpr int Q4 = (CD * CD) / 4;   // 1M elems in float4 units
__global__ __launch_bounds__(256) void k_convert_all(
        const float4* __restrict__ Wq, const float4* __restrict__ Wk,
        const float4* __restrict__ Wv, const float4* __restrict__ Wo,
        const float4* __restrict__ Ws, const float4* __restrict__ Wh,
        const float4* __restrict__ Wp1, const float4* __restrict__ Wp2,
        const float4* __restrict__ x, ushort4* __restrict__ arena,
        ushort4* __restrict__ xb) {
    int i = blockIdx.x * 256 + threadIdx.x;
    int stride = gridDim.x * 256;
    for (; i < 18 * Q4; i += stride) {
        const float4* src; int off; ushort4* dst;
        if (i < 6 * Q4) {
            if (i < 2 * Q4)      { if (i < Q4)     { src = Wq; off = i; }          else { src = Wk; off = i - Q4; } }
            else if (i < 4 * Q4) { if (i < 3 * Q4) { src = Wv; off = i - 2 * Q4; } else { src = Wo; off = i - 3 * Q4; } }
            else                 { if (i < 5 * Q4) { src = Ws; off = i - 4 * Q4; } else { src = Wh; off = i - 5 * Q4; } }
            dst = arena + i;
        } else if (i < 14 * Q4) {
            if (i < 10 * Q4) { src = Wp1; off = i - 6 * Q4; } else { src = Wp2; off = i - 10 * Q4; }
            dst = arena + i;
        } else {
            src = x; off = i - 14 * Q4; dst = xb + off;
        }
        float4 v = src[off];
        ushort4 o;
        o.x = f2bf(v.x); o.y = f2bf(v.y); o.z = f2bf(v.z); o.w = f2bf(v.w);
        *dst = o;
    }
}

__global__ __launch_bounds__(256) void k_zero(float* __restrict__ p, int n) {
    int i = blockIdx.x * 256 + threadIdx.x;
    int stride = gridDim.x * 256;
    for (; i < n; i += stride) p[i] = 0.f;
}

// ---------------- bf16 MFMA GEMM (m97-style): C[M,N] = A[M,K]*B[N,K]^T ----------------
// EPI 0: f32 out.  EPI 3: +bias, relu, bf16 out.
// SPLITK: blockIdx.z picks K-half; f32 C offset by z*M*N (halves summed downstream).
template <int EPI, int SPLITK>
__global__ __launch_bounds__(256) void k_gemm_bt(const ush* __restrict__ A,
                                                 const ush* __restrict__ Bm,
                                                 float* __restrict__ C,
                                                 ush* __restrict__ Cb,
                                                 const float* __restrict__ bias,
                                                 int N, int K) {
    __shared__ ush As[128 * 32];   // unpadded: lane-linear for global_load_lds
    __shared__ ush Bs[128 * 32];
    const int tid  = threadIdx.x;
    const int wave = tid >> 6, lane = tid & 63;
    const int quad = lane >> 4, r = lane & 15;
    const int wm = wave >> 1, wn = wave & 1;
    const int bm = blockIdx.x, bn = blockIdx.y;

    const int kcnt  = K / SPLITK;
    const int kbase = blockIdx.z * kcnt;
    if (SPLITK > 1) C += (size_t)blockIdx.z * (size_t)gridDim.x * 128 * N;

    const int srow = tid >> 2;        // 0..63
    const int scol = (tid & 3) * 8;   // k-offset, 8 elems = 16B
    const ush* aptr = A  + (size_t)(bm * 128 + srow) * K + kbase + scol;
    const ush* bptr = Bm + (size_t)(bn * 128 + srow) * K + kbase + scol;
    ush* asd = As + tid * 8;
    ush* bsd = Bs + tid * 8;
    const size_t rstep = (size_t)64 * K;

    f32x4 acc[4][4];
#pragma unroll
    for (int i = 0; i < 4; i++)
#pragma unroll
        for (int j = 0; j < 4; j++) acc[i][j] = (f32x4){0.f, 0.f, 0.f, 0.f};

    for (int k0 = 0; k0 < kcnt; k0 += 32) {
        gll16(aptr,         asd);
        gll16(aptr + rstep, asd + 2048);
        gll16(bptr,         bsd);
        gll16(bptr + rstep, bsd + 2048);
        aptr += 32; bptr += 32;
        __syncthreads();
        bf16x8 af[4], bfr[4];
#pragma unroll
        for (int i = 0; i < 4; i++) {
            af[i]  = *(const bf16x8*)(As + (wm * 64 + i * 16 + r) * 32 + quad * 8);
            bfr[i] = *(const bf16x8*)(Bs + (wn * 64 + i * 16 + r) * 32 + quad * 8);
        }
#pragma unroll
        for (int i = 0; i < 4; i++)
#pragma unroll
            for (int j = 0; j < 4; j++)
                acc[i][j] = __builtin_amdgcn_mfma_f32_16x16x32_bf16(af[i], bfr[j], acc[i][j], 0, 0, 0);
        __syncthreads();
    }

#pragma unroll
    for (int i = 0; i < 4; i++) {
        const int row0 = bm * 128 + wm * 64 + i * 16 + quad * 4;
#pragma unroll
        for (int j = 0; j < 4; j++) {
            const int col = bn * 128 + wn * 64 + j * 16 + r;
            float bv = (EPI == 3) ? bias[col] : 0.f;
#pragma unroll
            for (int g = 0; g < 4; g++) {
                float v = acc[i][j][g] + bv;
                size_t off = (size_t)(row0 + g) * N + col;
                if (EPI == 3) { v = fmaxf(v, 0.f); Cb[off] = f2bf(v); }
                else          { C[off] = v; }
            }
        }
    }
}

// ---------------- fused per-head LN for q,k,v from packed QKV [CNT][3072] ----------------
__global__ __launch_bounds__(256) void k_ln_head_qkv(float* __restrict__ qkv,
                                                     const float* __restrict__ gam,
                                                     const float* __restrict__ bet,
                                                     ush* __restrict__ qo,
                                                     ush* __restrict__ ko) {
    const int lane = threadIdx.x & 63;
    const int gid  = blockIdx.x * 4 + (threadIdx.x >> 6);  // over CNT*48
    const int t    = gid / 48;
    const int slot = gid - t * 48;
    const size_t src = (size_t)t * 3072 + slot * 64 + lane;
    float x = qkv[src];
    float s = x, q = x * x;
#pragma unroll
    for (int off = 32; off >= 1; off >>= 1) {
        s += __shfl_xor(s, off);
        q += __shfl_xor(q, off);
    }
    float mu  = s * (1.f / 64.f);
    float var = q * (1.f / 64.f) - mu * mu;
    float y = (x - mu) * rsqrtf(var + 1e-5f) * gam[lane] + bet[lane];
    const int which = slot >> 4, h = slot & 15;
    const size_t o = (size_t)t * CD + h * 64 + lane;
    if (which == 0)      qo[o] = f2bf(y);
    else if (which == 1) ko[o] = f2bf(y);
    else                 qkv[src] = y;   // v-ln stays f32 in place
}

// ---------------- banded attention column-sum kernel ----------------
// wcol[b,h,l] = sum_q softmax_row_q(pre)[l]  (rows with zero band mass contribute 0;
// the single all-masked row q=0 adds uniform 1/1024 in k_scale_v).
// Band: exp(pre-8) == 0 in fp32 for |q-l| > ~104, so 3 K-tiles of 64 suffice.
__global__ __launch_bounds__(256) void k_attn(const ush* __restrict__ qb,
                                              const ush* __restrict__ kb,
                                              const float* __restrict__ mask,
                                              float* __restrict__ wcol) {
    __shared__ ush   Qs[64][72];
    __shared__ ush   Ks[64][72];
    __shared__ float colpart[4][64];

    const int tid  = threadIdx.x;
    const int wave = tid >> 6, lane = tid & 63;
    const int quad = lane >> 4, r = lane & 15;
    const int bh = blockIdx.x, bi = bh >> 4, hi = bh & 15;
    const int q0 = blockIdx.y * 64;

    {
        int row = tid >> 2, seg = (tid & 3) * 16;
        const ush* src = qb + ((size_t)(bi * CS + q0 + row) * CD + hi * 64 + seg);
        *(uint4*)&Qs[row][seg]     = *(const uint4*)src;
        *(uint4*)&Qs[row][seg + 8] = *(const uint4*)(src + 8);
    }
    __syncthreads();
    bf16x8 af0 = *(const bf16x8*)&Qs[wave * 16 + r][quad * 8];
    bf16x8 af1 = *(const bf16x8*)&Qs[wave * 16 + r][32 + quad * 8];

    float mq[4];
#pragma unroll
    for (int g = 0; g < 4; g++) mq[g] = mask[bi * CS + q0 + wave * 16 + quad * 4 + g];

    const int t0 = (q0 >= 128) ? 0 : ((q0 >= 64) ? 1 : 2);
    float pr[3][4][4];
    float s_loc[4] = {0.f, 0.f, 0.f, 0.f};

    for (int t = t0; t < 3; t++) {
        const int l0 = q0 - 128 + t * 64;
        __syncthreads();
        {
            int row = tid >> 2, seg = (tid & 3) * 16;
            const ush* src = kb + ((size_t)(bi * CS + l0 + row) * CD + hi * 64 + seg);
            *(uint4*)&Ks[row][seg]     = *(const uint4*)src;
            *(uint4*)&Ks[row][seg + 8] = *(const uint4*)(src + 8);
        }
        __syncthreads();
#pragma unroll
        for (int jt = 0; jt < 4; jt++) {
            bf16x8 bf0 = *(const bf16x8*)&Ks[jt * 16 + r][quad * 8];
            bf16x8 bf1 = *(const bf16x8*)&Ks[jt * 16 + r][32 + quad * 8];
            f32x4 sc = (f32x4){0.f, 0.f, 0.f, 0.f};
            sc = __builtin_amdgcn_mfma_f32_16x16x32_bf16(af0, bf0, sc, 0, 0, 0);
            sc = __builtin_amdgcn_mfma_f32_16x16x32_bf16(af1, bf1, sc, 0, 0, 0);
            const int l = l0 + jt * 16 + r;
            const float ml = mask[bi * CS + l];
#pragma unroll
            for (int g = 0; g < 4; g++) {
                const int qg = q0 + wave * 16 + quad * 4 + g;
                float e  = sc[g] * 0.03125f;
                float mv = (qg > l) ? 0.f : mq[g] * ml * (-1e20f);
                float p  = __expf(e + mv - fabsf((float)(qg - l)) - 8.f);
                pr[t][jt][g] = p;
                s_loc[g] += p;
            }
        }
    }

    float rs[4];
#pragma unroll
    for (int g = 0; g < 4; g++) {
        float s = s_loc[g];
        s += __shfl_xor(s, 1); s += __shfl_xor(s, 2);
        s += __shfl_xor(s, 4); s += __shfl_xor(s, 8);
        rs[g] = (s > 0.f) ? 1.f / s : 0.f;
    }

    for (int t = t0; t < 3; t++) {
        const int l0 = q0 - 128 + t * 64;
#pragma unroll
        for (int jt = 0; jt < 4; jt++) {
            float csum = 0.f;
#pragma unroll
            for (int g = 0; g < 4; g++) csum += pr[t][jt][g] * rs[g];
            csum += __shfl_xor(csum, 16);
            csum += __shfl_xor(csum, 32);
            if (quad == 0) colpart[wave][jt * 16 + r] = csum;
        }
        __syncthreads();
        if (tid < 64) {
            float v = colpart[0][tid] + colpart[1][tid] + colpart[2][tid] + colpart[3][tid];
            atomicAdd(&wcol[(size_t)bh * CS + l0 + tid], v);
        }
        __syncthreads();
    }
}

// ---------------- scale v by column weights (+ uniform row-0 term) ----------------
__global__ __launch_bounds__(256) void k_scale_v(const float* __restrict__ qkv,
                                                 const float* __restrict__ wcol,
                                                 ush* __restrict__ out) {
    int i = blockIdx.x * 256 + threadIdx.x;
    int stride = gridDim.x * 256;
    for (; i < CNT * CD; i += stride) {
        int token = i >> 10;
        int c = i & (CD - 1);
        int l = token & (CS - 1);
        int b = token >> 10;
        int h = c >> 6;
        float w = wcol[(size_t)(b * CH + h) * CS + l] + (1.f / 1024.f);
        out[i] = f2bf(w * qkv[(size_t)token * 3072 + 2048 + c]);
    }
}

// ---------------- row layernorm over D=1024, fused variants ----------------
// MODE 0: LN(in0+in1+badd) -> bf16 outb                       (Wo split halves + bo)
// MODE 1: LN(in0+in1) -> f32 outf                             (Ws halves)
// MODE 2: sf=in0; hf=LN(in1+in2); f=sigmoid(sf+hf+badd);
//         LN(f*sf+(1-f)*hf) -> f32 outf + bf16 outb           (gate; Wh halves inline-LN'd)
// MODE 3: LN(in0+in1+in2+badd) -> f32 outf                    (final: FFN2 halves + bp2 + g)
__device__ __forceinline__ void blk_stats(float s, float q, float* red,
                                          int wave, int lane, float& mu, float& rstd) {
#pragma unroll
    for (int off = 32; off >= 1; off >>= 1) {
        s += __shfl_xor(s, off);
        q += __shfl_xor(q, off);
    }
    if (lane == 0) { red[wave] = s; red[4 + wave] = q; }
    __syncthreads();
    s = red[0] + red[1] + red[2] + red[3];
    q = red[4] + red[5] + red[6] + red[7];
    mu = s * (1.f / 1024.f);
    rstd = rsqrtf(q * (1.f / 1024.f) - mu * mu + 1e-5f);
    __syncthreads();
}

template <int MODE>
__global__ __launch_bounds__(256) void k_ln_row(const float* __restrict__ in0,
                                                const float* __restrict__ in1,
                                                const float* __restrict__ in2,
                                                const float* __restrict__ badd,
                                                const float* __restrict__ gam,
                                                const float* __restrict__ bet,
                                                float* __restrict__ outf,
                                                ush* __restrict__ outb) {
    __shared__ float red[8];
    const int tid = threadIdx.x, wave = tid >> 6, lane = tid & 63;
    const size_t base = (size_t)blockIdx.x * CD;
    float t[4], sf[4];
#pragma unroll
    for (int j = 0; j < 4; j++) {
        int col = tid + j * 256;
        if (MODE == 0)      t[j] = in0[base + col] + in1[base + col] + badd[col];
        else if (MODE == 1) t[j] = in0[base + col] + in1[base + col];
        else if (MODE == 2) { sf[j] = in0[base + col]; t[j] = in1[base + col] + in2[base + col]; }
        else                t[j] = in0[base + col] + in1[base + col] + in2[base + col] + badd[col];
    }
    float s = 0.f, q = 0.f, mu, rstd;
#pragma unroll
    for (int j = 0; j < 4; j++) { s += t[j]; q += t[j] * t[j]; }
    blk_stats(s, q, red, wave, lane, mu, rstd);

    if (MODE == 2) {
        // t currently = raw h@Wh halves sum -> inline LN to h_f, then gate
#pragma unroll
        for (int j = 0; j < 4; j++) {
            int col = tid + j * 256;
            float hf = (t[j] - mu) * rstd * gam[col] + bet[col];
            float f  = 1.f / (1.f + __expf(-(sf[j] + hf + badd[col])));
            t[j] = f * sf[j] + (1.f - f) * hf;
        }
        s = 0.f; q = 0.f;
#pragma unroll
        for (int j = 0; j < 4; j++) { s += t[j]; q += t[j] * t[j]; }
        blk_stats(s, q, red, wave, lane, mu, rstd);
    }

#pragma unroll
    for (int j = 0; j < 4; j++) {
        int col = tid + j * 256;
        float y = (t[j] - mu) * rstd * gam[col] + bet[col];
        if (MODE == 0)      outb[base + col] = f2bf(y);
        else if (MODE == 1) outf[base + col] = y;
        else if (MODE == 2) { outf[base + col] = y; outb[base + col] = f2bf(y); }
        else                outf[base + col] = y;
    }
}

// ---------------- host launch ----------------
extern "C" void kernel_launch(void* const* d_in, const int* in_sizes, int n_in,
                              void* d_out, int out_size, void* d_ws, size_t ws_size,
                              hipStream_t stream) {
    const float* x    = (const float*)d_in[0];
    const float* mask = (const float*)d_in[1];
    const float* Wq   = (const float*)d_in[2];
    const float* Wk   = (const float*)d_in[3];
    const float* Wv   = (const float*)d_in[4];
    const float* ln1g = (const float*)d_in[5];
    const float* ln1b = (const float*)d_in[6];
    const float* Wo   = (const float*)d_in[7];
    const float* bo   = (const float*)d_in[8];
    const float* ln2g = (const float*)d_in[9];
    const float* ln2b = (const float*)d_in[10];
    const float* Ws   = (const float*)d_in[11];
    const float* Wh   = (const float*)d_in[12];
    const float* bf_  = (const float*)d_in[13];
    const float* lnfgg = (const float*)d_in[14];
    const float* lnfgb = (const float*)d_in[15];
    const float* Wp1  = (const float*)d_in[16];
    const float* bp1  = (const float*)d_in[17];
    const float* Wp2  = (const float*)d_in[18];
    const float* bp2  = (const float*)d_in[19];
    const float* lnffg = (const float*)d_in[20];
    const float* lnffb = (const float*)d_in[21];
    float* out = (float*)d_out;

    char* p = (char*)d_ws;
    auto alloc = [&](size_t bytes) -> char* {
        char* r = p;
        p += (bytes + 255) & ~(size_t)255;
        return r;
    };
    // weights arena: Wqkv(3M) Wo(1M) Ws(1M) Wh(1M) Wp1(4M) Wp2(4M) elements, contiguous
    ush*   arena = (ush*)alloc((size_t)14 * CD * CD * 2);
    ush*   Wqkvb = arena;
    ush*   Wob   = arena + (size_t)3 * CD * CD;
    ush*   Wsb   = arena + (size_t)4 * CD * CD;
    ush*   Whb   = arena + (size_t)5 * CD * CD;
    ush*   Wp1b  = arena + (size_t)6 * CD * CD;
    ush*   Wp2b  = arena + (size_t)10 * CD * CD;
    ush*   xb    = (ush*)alloc((size_t)CNT * CD * 2);
    float* qkv   = (float*)alloc((size_t)CNT * 3072 * 4);  // also hosts P0/P1/bufS later
    float* P0    = qkv;
    float* P1    = qkv + (size_t)CNT * CD;
    float* bufS  = qkv + (size_t)2 * CNT * CD;
    ush*   qlnb  = (ush*)alloc((size_t)CNT * CD * 2);
    ush*   klnb  = (ush*)alloc((size_t)CNT * CD * 2);
    ush*   gb    = (ush*)alloc((size_t)CNT * CD * 2);
    ush*   ff1b  = (ush*)alloc((size_t)CNT * CDFF * 2);
    float* bufG  = (float*)alloc((size_t)CNT * CD * 4);
    float* wcol  = (float*)alloc((size_t)CB * CH * CS * 4);
    ush* attb = qlnb;  // alias: q-ln consumed by k_attn before k_scale_v writes
    ush* hb   = klnb;  // alias: k-ln consumed by k_attn before ln_row<0> writes

    dim3 blk(256);

    // conversions (1 launch)
    k_convert_all<<<dim3(8192), blk, 0, stream>>>(
        (const float4*)Wq, (const float4*)Wk, (const float4*)Wv, (const float4*)Wo,
        (const float4*)Ws, (const float4*)Wh, (const float4*)Wp1, (const float4*)Wp2,
        (const float4*)x, (ushort4*)arena, (ushort4*)xb);

    // fused QKV projection: C[4096,3072]
    k_gemm_bt<0, 1><<<dim3(32, 24, 1), blk, 0, stream>>>(xb, Wqkvb, qkv, nullptr, nullptr, 3072, CD);
    k_ln_head_qkv<<<dim3(CNT * 48 / 4), blk, 0, stream>>>(qkv, ln1g, ln1b, qlnb, klnb);

    // attention column sums (banded)
    k_zero<<<dim3(64), blk, 0, stream>>>(wcol, CB * CH * CS);
    k_attn<<<dim3(CB * CH, CS / 64), blk, 0, stream>>>(qlnb, klnb, mask, wcol);
    k_scale_v<<<dim3(4096), blk, 0, stream>>>(qkv, wcol, attb);

    // output projection (split-K=2) + LN2 (+bo)
    k_gemm_bt<0, 2><<<dim3(32, 8, 2), blk, 0, stream>>>(attb, Wob, P0, nullptr, nullptr, CD, CD);
    k_ln_row<0><<<dim3(CNT), blk, 0, stream>>>(P0, P1, nullptr, bo, ln2g, ln2b, nullptr, hb);

    // fusion gate: s_f, then h_f inline in gate kernel
    k_gemm_bt<0, 2><<<dim3(32, 8, 2), blk, 0, stream>>>(xb, Wsb, P0, nullptr, nullptr, CD, CD);
    k_ln_row<1><<<dim3(CNT), blk, 0, stream>>>(P0, P1, nullptr, nullptr, lnfgg, lnfgb, bufS, nullptr);
    k_gemm_bt<0, 2><<<dim3(32, 8, 2), blk, 0, stream>>>(hb, Whb, P0, nullptr, nullptr, CD, CD);
    k_ln_row<2><<<dim3(CNT), blk, 0, stream>>>(bufS, P0, P1, bf_, lnfgg, lnfgb, bufG, gb);

    // FFN + residual + final LN (+bp2)
    k_gemm_bt<3, 1><<<dim3(32, 32, 1), blk, 0, stream>>>(gb, Wp1b, nullptr, ff1b, bp1, CDFF, CD);
    k_gemm_bt<0, 2><<<dim3(32, 8, 2), blk, 0, stream>>>(ff1b, Wp2b, P0, nullptr, nullptr, CD, CDFF);
    k_ln_row<3><<<dim3(CNT), blk, 0, stream>>>(P0, P1, bufG, bp2, lnffg, lnffb, out, nullptr);

    (void)in_sizes; (void)n_in; (void)out_size; (void)ws_size;
}

// Round 3
// 381.010 us; speedup vs baseline: 1.8238x; 1.2122x over previous
//
#include <hip/hip_runtime.h>

// ---------------- problem constants ----------------
constexpr int CB   = 4;
constexpr int CS   = 1024;
constexpr int CD   = 1024;
constexpr int CH   = 16;
constexpr int CDFF = 4096;
constexpr int CNT  = CB * CS;   // 4096 tokens

typedef unsigned short ush;
typedef __bf16 bf16_t;
typedef bf16_t bf16x8 __attribute__((ext_vector_type(8)));
typedef float  f32x4  __attribute__((ext_vector_type(4)));

__device__ __forceinline__ ush f2bf(float f) {
    union { float f; unsigned u; } v; v.f = f;
    unsigned u = v.u;
    return (ush)((u + 0x7fffu + ((u >> 16) & 1u)) >> 16);
}
__device__ __forceinline__ float bf2f(ush h) {
    union { unsigned u; float f; } v; v.u = ((unsigned)h) << 16;
    return v.f;
}

// async global->LDS, 16B per lane (dest = wave-uniform base + lane*16)
__device__ __forceinline__ void gll16(const void* g, void* l) {
    __builtin_amdgcn_global_load_lds((const __attribute__((address_space(1))) void*)g,
                                     (__attribute__((address_space(3))) void*)l,
                                     16, 0, 0);
}

// ---------------- fused conversions (x + all weights) ----------------
// arena (elements): [Wq 1M | Wk 1M | Wv 1M | Ws 1M | Wo 1M | Wh 1M | Wp1 4M | Wp2 4M]
constexpr int Q4 = (CD * CD) / 4;
__global__ __launch_bounds__(256) void k_convert_all(
        const float4* __restrict__ Wq, const float4* __restrict__ Wk,
        const float4* __restrict__ Wv, const float4* __restrict__ Ws,
        const float4* __restrict__ Wo, const float4* __restrict__ Wh,
        const float4* __restrict__ Wp1, const float4* __restrict__ Wp2,
        const float4* __restrict__ x, ushort4* __restrict__ arena,
        ushort4* __restrict__ xb) {
    int i = blockIdx.x * 256 + threadIdx.x;
    int stride = gridDim.x * 256;
    for (; i < 18 * Q4; i += stride) {
        const float4* src; int off; ushort4* dst;
        if (i < 4 * Q4) {
            if (i < 2 * Q4) { if (i < Q4)     { src = Wq; off = i; }          else { src = Wk; off = i - Q4; } }
            else            { if (i < 3 * Q4) { src = Wv; off = i - 2 * Q4; } else { src = Ws; off = i - 3 * Q4; } }
            dst = arena + i;
        } else if (i < 6 * Q4) {
            if (i < 5 * Q4) { src = Wo; off = i - 4 * Q4; } else { src = Wh; off = i - 5 * Q4; }
            dst = arena + i;
        } else if (i < 14 * Q4) {
            if (i < 10 * Q4) { src = Wp1; off = i - 6 * Q4; } else { src = Wp2; off = i - 10 * Q4; }
            dst = arena + i;
        } else {
            src = x; off = i - 14 * Q4; dst = xb + off;
        }
        float4 v = src[off];
        ushort4 o;
        o.x = f2bf(v.x); o.y = f2bf(v.y); o.z = f2bf(v.z); o.w = f2bf(v.w);
        *dst = o;
    }
}

__global__ __launch_bounds__(256) void k_zero(float* __restrict__ p, int n) {
    int i = blockIdx.x * 256 + threadIdx.x;
    int stride = gridDim.x * 256;
    for (; i < n; i += stride) p[i] = 0.f;
}

// ---------------- bf16 MFMA GEMM: C[M,N] = A[M,K]*B[N,K]^T ----------------
// BK=64, XOR-swizzled LDS (conflict-free gll16 writes AND b128 frag reads).
// TN: 128 or 64 (tile cols). EPI: 0 = f32 out; 3 = +bias relu bf16 out;
// 4 = QKVS fused per-head-LN epilogue (N=4096 hardcoded segments).
// SPLITK: blockIdx.z picks K-slice; f32 C offset by z*M*N.
template <int TN, int EPI, int SPLITK>
__global__ __launch_bounds__(256, 4) void k_gemm_bt(
        const ush* __restrict__ A, const ush* __restrict__ Bm,
        float* __restrict__ C, ush* __restrict__ Cb,
        const float* __restrict__ bias, const float* __restrict__ bias2,
        ush* __restrict__ out2, ush* __restrict__ out3,
        int N, int K) {
    constexpr int NJ  = TN / 32;   // j-frags per wave
    constexpr int BCH = TN / 32;   // B staging chunks (32 rows each)
    __shared__ ush As[128 * 64];
    __shared__ ush Bs[TN * 64];
    const int tid  = threadIdx.x;
    const int wave = tid >> 6, lane = tid & 63;
    const int quad = lane >> 4, r = lane & 15;
    const int wm = wave >> 1, wn = wave & 1;
    const int bm = blockIdx.x, bn = blockIdx.y;

    const int kcnt  = K / SPLITK;
    const int kbase = blockIdx.z * kcnt;
    if (SPLITK > 1) C += (size_t)blockIdx.z * (size_t)gridDim.x * 128 * N;

    // staging: thread t loads element (row = t/8 + c*32, k-chunk kcl = (t&7) ^ (row&7))
    // logical LDS layout: (row, kc) at ush offset row*64 + (kc ^ (row&7))*8
    const int trow = tid >> 3, tk8 = tid & 7;
    const int kcl  = tk8 ^ (trow & 7);
    const ush* ap = A  + (size_t)(bm * 128 + trow) * K + kbase + kcl * 8;
    const ush* bp = Bm + (size_t)(bn * TN  + trow) * K + kbase + kcl * 8;
    ush* asd = As + tid * 8;
    ush* bsd = Bs + tid * 8;
    const size_t cstep = (size_t)32 * K;

    f32x4 acc[4][NJ];
#pragma unroll
    for (int i = 0; i < 4; i++)
#pragma unroll
        for (int j = 0; j < NJ; j++) acc[i][j] = (f32x4){0.f, 0.f, 0.f, 0.f};

    const int rx = r & 7;
    for (int k0 = 0; k0 < kcnt; k0 += 64) {
#pragma unroll
        for (int c = 0; c < 4; c++)   gll16(ap + c * cstep, asd + c * 2048);
#pragma unroll
        for (int c = 0; c < BCH; c++) gll16(bp + c * cstep, bsd + c * 2048);
        ap += 64; bp += 64;
        __syncthreads();
#pragma unroll
        for (int h = 0; h < 2; h++) {
            const int kx = (((h << 2) | quad) ^ rx) * 8;
            bf16x8 af[4], bfv[NJ];
#pragma unroll
            for (int i = 0; i < 4; i++)
                af[i] = *(const bf16x8*)(As + (wm * 64 + i * 16 + r) * 64 + kx);
#pragma unroll
            for (int j = 0; j < NJ; j++)
                bfv[j] = *(const bf16x8*)(Bs + (wn * (TN / 2) + j * 16 + r) * 64 + kx);
#pragma unroll
            for (int i = 0; i < 4; i++)
#pragma unroll
                for (int j = 0; j < NJ; j++)
                    acc[i][j] = __builtin_amdgcn_mfma_f32_16x16x32_bf16(af[i], bfv[j], acc[i][j], 0, 0, 0);
        }
        __syncthreads();
    }

    if (EPI == 4) {
        // QKVS: bn<8 -> q, <16 -> k, <24 -> v (per-head LN -> bf16); else s -> f32 [CNT][1024]
        if (bn >= 24) {
            const int colb = (bn - 24) * 128 + wn * 64;
#pragma unroll
            for (int i = 0; i < 4; i++) {
                const int row0 = bm * 128 + wm * 64 + i * 16 + quad * 4;
#pragma unroll
                for (int j = 0; j < NJ; j++) {
                    const int col = colb + j * 16 + r;
#pragma unroll
                    for (int g = 0; g < 4; g++)
                        C[(size_t)(row0 + g) * 1024 + col] = acc[i][j][g];
                }
            }
        } else {
            float g4[4], b4[4];
#pragma unroll
            for (int j = 0; j < 4; j++) { g4[j] = bias[j * 16 + r]; b4[j] = bias2[j * 16 + r]; }
            ush* dst; int cb0 = bn * 128 + wn * 64;
            if (bn < 8)       dst = Cb;
            else if (bn < 16) { dst = out2; cb0 -= 1024; }
            else              { dst = out3; cb0 -= 2048; }
#pragma unroll
            for (int i = 0; i < 4; i++) {
                const int row0 = bm * 128 + wm * 64 + i * 16 + quad * 4;
#pragma unroll
                for (int g = 0; g < 4; g++) {
                    float s = 0.f, q = 0.f;
#pragma unroll
                    for (int j = 0; j < 4; j++) { float v = acc[i][j][g]; s += v; q += v * v; }
                    s += __shfl_xor(s, 1); q += __shfl_xor(q, 1);
                    s += __shfl_xor(s, 2); q += __shfl_xor(q, 2);
                    s += __shfl_xor(s, 4); q += __shfl_xor(q, 4);
                    s += __shfl_xor(s, 8); q += __shfl_xor(q, 8);
                    float mu   = s * (1.f / 64.f);
                    float rstd = rsqrtf(q * (1.f / 64.f) - mu * mu + 1e-5f);
#pragma unroll
                    for (int j = 0; j < 4; j++) {
                        float y = (acc[i][j][g] - mu) * rstd * g4[j] + b4[j];
                        dst[(size_t)(row0 + g) * 1024 + cb0 + j * 16 + r] = f2bf(y);
                    }
                }
            }
        }
    } else {
#pragma unroll
        for (int i = 0; i < 4; i++) {
            const int row0 = bm * 128 + wm * 64 + i * 16 + quad * 4;
#pragma unroll
            for (int j = 0; j < NJ; j++) {
                const int col = bn * TN + wn * (TN / 2) + j * 16 + r;
                float bv = (EPI == 3) ? bias[col] : 0.f;
#pragma unroll
                for (int g = 0; g < 4; g++) {
                    float v = acc[i][j][g] + bv;
                    size_t off = (size_t)(row0 + g) * N + col;
                    if (EPI == 3) { v = fmaxf(v, 0.f); Cb[off] = f2bf(v); }
                    else          { C[off] = v; }
                }
            }
        }
    }
}

// ---------------- banded attention column-sum kernel ----------------
// wcol[b,h,l] = sum_q softmax_row_q(pre)[l]; exp(pre-8)==0 in fp32 for |q-l|>~104,
// so 3 K-tiles of 64 suffice. All-masked row q=0 adds uniform 1/1024 in k_scale_v.
__global__ __launch_bounds__(256) void k_attn(const ush* __restrict__ qb,
                                              const ush* __restrict__ kb,
                                              const float* __restrict__ mask,
                                              float* __restrict__ wcol) {
    __shared__ ush   Qs[64][72];
    __shared__ ush   Ks[64][72];
    __shared__ float colpart[4][64];

    const int tid  = threadIdx.x;
    const int wave = tid >> 6, lane = tid & 63;
    const int quad = lane >> 4, r = lane & 15;
    const int bh = blockIdx.x, bi = bh >> 4, hi = bh & 15;
    const int q0 = blockIdx.y * 64;

    {
        int row = tid >> 2, seg = (tid & 3) * 16;
        const ush* src = qb + ((size_t)(bi * CS + q0 + row) * CD + hi * 64 + seg);
        *(uint4*)&Qs[row][seg]     = *(const uint4*)src;
        *(uint4*)&Qs[row][seg + 8] = *(const uint4*)(src + 8);
    }
    __syncthreads();
    bf16x8 af0 = *(const bf16x8*)&Qs[wave * 16 + r][quad * 8];
    bf16x8 af1 = *(const bf16x8*)&Qs[wave * 16 + r][32 + quad * 8];

    float mq[4];
#pragma unroll
    for (int g = 0; g < 4; g++) mq[g] = mask[bi * CS + q0 + wave * 16 + quad * 4 + g];

    const int t0 = (q0 >= 128) ? 0 : ((q0 >= 64) ? 1 : 2);
    float pr[3][4][4];
    float s_loc[4] = {0.f, 0.f, 0.f, 0.f};

    for (int t = t0; t < 3; t++) {
        const int l0 = q0 - 128 + t * 64;
        __syncthreads();
        {
            int row = tid >> 2, seg = (tid & 3) * 16;
            const ush* src = kb + ((size_t)(bi * CS + l0 + row) * CD + hi * 64 + seg);
            *(uint4*)&Ks[row][seg]     = *(const uint4*)src;
            *(uint4*)&Ks[row][seg + 8] = *(const uint4*)(src + 8);
        }
        __syncthreads();
#pragma unroll
        for (int jt = 0; jt < 4; jt++) {
            bf16x8 bf0 = *(const bf16x8*)&Ks[jt * 16 + r][quad * 8];
            bf16x8 bf1 = *(const bf16x8*)&Ks[jt * 16 + r][32 + quad * 8];
            f32x4 sc = (f32x4){0.f, 0.f, 0.f, 0.f};
            sc = __builtin_amdgcn_mfma_f32_16x16x32_bf16(af0, bf0, sc, 0, 0, 0);
            sc = __builtin_amdgcn_mfma_f32_16x16x32_bf16(af1, bf1, sc, 0, 0, 0);
            const int l = l0 + jt * 16 + r;
            const float ml = mask[bi * CS + l];
#pragma unroll
            for (int g = 0; g < 4; g++) {
                const int qg = q0 + wave * 16 + quad * 4 + g;
                float e  = sc[g] * 0.03125f;
                float mv = (qg > l) ? 0.f : mq[g] * ml * (-1e20f);
                float p  = __expf(e + mv - fabsf((float)(qg - l)) - 8.f);
                pr[t][jt][g] = p;
                s_loc[g] += p;
            }
        }
    }

    float rs[4];
#pragma unroll
    for (int g = 0; g < 4; g++) {
        float s = s_loc[g];
        s += __shfl_xor(s, 1); s += __shfl_xor(s, 2);
        s += __shfl_xor(s, 4); s += __shfl_xor(s, 8);
        rs[g] = (s > 0.f) ? 1.f / s : 0.f;
    }

    for (int t = t0; t < 3; t++) {
        const int l0 = q0 - 128 + t * 64;
#pragma unroll
        for (int jt = 0; jt < 4; jt++) {
            float csum = 0.f;
#pragma unroll
            for (int g = 0; g < 4; g++) csum += pr[t][jt][g] * rs[g];
            csum += __shfl_xor(csum, 16);
            csum += __shfl_xor(csum, 32);
            if (quad == 0) colpart[wave][jt * 16 + r] = csum;
        }
        __syncthreads();
        if (tid < 64) {
            float v = colpart[0][tid] + colpart[1][tid] + colpart[2][tid] + colpart[3][tid];
            atomicAdd(&wcol[(size_t)bh * CS + l0 + tid], v);
        }
        __syncthreads();
    }
}

// ---------------- scale v by column weights (+ uniform row-0 term) ----------------
__global__ __launch_bounds__(256) void k_scale_v(const ush* __restrict__ vb,
                                                 const float* __restrict__ wcol,
                                                 ush* __restrict__ out) {
    int i = blockIdx.x * 256 + threadIdx.x;
    int stride = gridDim.x * 256;
    for (; i < CNT * CD; i += stride) {
        int token = i >> 10;
        int c = i & (CD - 1);
        int l = token & (CS - 1);
        int b = token >> 10;
        int h = c >> 6;
        float w = wcol[(size_t)(b * CH + h) * CS + l] + (1.f / 1024.f);
        out[i] = f2bf(w * bf2f(vb[i]));
    }
}

// ---------------- row layernorm over D=1024, fused variants ----------------
// MODE 0: LN(in0+in1+badd) -> bf16 outb
// MODE 1: LN(in0) -> f32 outf
// MODE 2: sf=in0; hf=LN(in1+in2); f=sigmoid(sf+hf+badd); LN(f*sf+(1-f)*hf) -> f32+bf16
// MODE 3: LN(in0+in1+in2+badd) -> f32 outf
__device__ __forceinline__ void blk_stats(float s, float q, float* red,
                                          int wave, int lane, float& mu, float& rstd) {
#pragma unroll
    for (int off = 32; off >= 1; off >>= 1) {
        s += __shfl_xor(s, off);
        q += __shfl_xor(q, off);
    }
    if (lane == 0) { red[wave] = s; red[4 + wave] = q; }
    __syncthreads();
    s = red[0] + red[1] + red[2] + red[3];
    q = red[4] + red[5] + red[6] + red[7];
    mu = s * (1.f / 1024.f);
    rstd = rsqrtf(q * (1.f / 1024.f) - mu * mu + 1e-5f);
    __syncthreads();
}

template <int MODE>
__global__ __launch_bounds__(256) void k_ln_row(const float* __restrict__ in0,
                                                const float* __restrict__ in1,
                                                const float* __restrict__ in2,
                                                const float* __restrict__ badd,
                                                const float* __restrict__ gam,
                                                const float* __restrict__ bet,
                                                float* __restrict__ outf,
                                                ush* __restrict__ outb) {
    __shared__ float red[8];
    const int tid = threadIdx.x, wave = tid >> 6, lane = tid & 63;
    const size_t base = (size_t)blockIdx.x * CD;
    float t[4], sf[4];
#pragma unroll
    for (int j = 0; j < 4; j++) {
        int col = tid + j * 256;
        if (MODE == 0)      t[j] = in0[base + col] + in1[base + col] + badd[col];
        else if (MODE == 1) t[j] = in0[base + col];
        else if (MODE == 2) { sf[j] = in0[base + col]; t[j] = in1[base + col] + in2[base + col]; }
        else                t[j] = in0[base + col] + in1[base + col] + in2[base + col] + badd[col];
    }
    float s = 0.f, q = 0.f, mu, rstd;
#pragma unroll
    for (int j = 0; j < 4; j++) { s += t[j]; q += t[j] * t[j]; }
    blk_stats(s, q, red, wave, lane, mu, rstd);

    if (MODE == 2) {
#pragma unroll
        for (int j = 0; j < 4; j++) {
            int col = tid + j * 256;
            float hf = (t[j] - mu) * rstd * gam[col] + bet[col];
            float f  = 1.f / (1.f + __expf(-(sf[j] + hf + badd[col])));
            t[j] = f * sf[j] + (1.f - f) * hf;
        }
        s = 0.f; q = 0.f;
#pragma unroll
        for (int j = 0; j < 4; j++) { s += t[j]; q += t[j] * t[j]; }
        blk_stats(s, q, red, wave, lane, mu, rstd);
    }

#pragma unroll
    for (int j = 0; j < 4; j++) {
        int col = tid + j * 256;
        float y = (t[j] - mu) * rstd * gam[col] + bet[col];
        if (MODE == 0)      outb[base + col] = f2bf(y);
        else if (MODE == 1) outf[base + col] = y;
        else if (MODE == 2) { outf[base + col] = y; outb[base + col] = f2bf(y); }
        else                outf[base + col] = y;
    }
}

// ---------------- host launch ----------------
extern "C" void kernel_launch(void* const* d_in, const int* in_sizes, int n_in,
                              void* d_out, int out_size, void* d_ws, size_t ws_size,
                              hipStream_t stream) {
    const float* x    = (const float*)d_in[0];
    const float* mask = (const float*)d_in[1];
    const float* Wq   = (const float*)d_in[2];
    const float* Wk   = (const float*)d_in[3];
    const float* Wv   = (const float*)d_in[4];
    const float* ln1g = (const float*)d_in[5];
    const float* ln1b = (const float*)d_in[6];
    const float* Wo   = (const float*)d_in[7];
    const float* bo   = (const float*)d_in[8];
    const float* ln2g = (const float*)d_in[9];
    const float* ln2b = (const float*)d_in[10];
    const float* Ws   = (const float*)d_in[11];
    const float* Wh   = (const float*)d_in[12];
    const float* bf_  = (const float*)d_in[13];
    const float* lnfgg = (const float*)d_in[14];
    const float* lnfgb = (const float*)d_in[15];
    const float* Wp1  = (const float*)d_in[16];
    const float* bp1  = (const float*)d_in[17];
    const float* Wp2  = (const float*)d_in[18];
    const float* bp2  = (const float*)d_in[19];
    const float* lnffg = (const float*)d_in[20];
    const float* lnffb = (const float*)d_in[21];
    float* out = (float*)d_out;

    char* p = (char*)d_ws;
    auto alloc = [&](size_t bytes) -> char* {
        char* r = p;
        p += (bytes + 255) & ~(size_t)255;
        return r;
    };
    ush*   arena = (ush*)alloc((size_t)14 * CD * CD * 2);  // 28 MB
    ush*   Wob   = arena + (size_t)4 * CD * CD;
    ush*   Whb   = arena + (size_t)5 * CD * CD;
    ush*   Wp1b  = arena + (size_t)6 * CD * CD;
    ush*   Wp2b  = arena + (size_t)10 * CD * CD;
    ush*   xb    = (ush*)alloc((size_t)CNT * CD * 2);      // 8 MB
    ush*   klnb  = (ush*)alloc((size_t)CNT * CD * 2);      // 8 MB  (hb alias)
    ush*   vb    = (ush*)alloc((size_t)CNT * CD * 2);      // 8 MB  \ bufG spans
    ush*   qlnb  = (ush*)alloc((size_t)CNT * CD * 2);      // 8 MB  / these two
    ush*   gb    = (ush*)alloc((size_t)CNT * CD * 2);      // 8 MB
    float* P0    = (float*)alloc((size_t)2 * CNT * CD * 4);// 32 MB (split-K partials)
    float* P1    = P0 + (size_t)CNT * CD;
    ush*   ff1b  = (ush*)alloc((size_t)CNT * CDFF * 2);    // 32 MB (sbuf aliases front)
    float* bufS  = (float*)alloc((size_t)CNT * CD * 4);    // 16 MB
    float* wcol  = (float*)alloc((size_t)CB * CH * CS * 4);
    float* sbuf  = (float*)ff1b;   // x@Ws f32; dead before FFN1 writes ff1b
    ush*   attb  = qlnb;           // q-ln consumed by k_attn before k_scale_v writes
    ush*   hb    = klnb;           // k-ln consumed by k_attn before ln_row<0> writes
    float* bufG  = (float*)vb;     // spans vb+qlnb (16 MB); both dead post-Wo

    dim3 blk(256);

    k_convert_all<<<dim3(8192), blk, 0, stream>>>(
        (const float4*)Wq, (const float4*)Wk, (const float4*)Wv, (const float4*)Ws,
        (const float4*)Wo, (const float4*)Wh, (const float4*)Wp1, (const float4*)Wp2,
        (const float4*)x, (ushort4*)arena, (ushort4*)xb);

    // fused QKVS projection + per-head LN epilogue (q,k,v -> bf16; s -> f32)
    k_gemm_bt<128, 4, 1><<<dim3(32, 32, 1), blk, 0, stream>>>(
        xb, arena, sbuf, qlnb, ln1g, ln1b, klnb, vb, 4096, CD);

    // s_f = LN(x@Ws)
    k_ln_row<1><<<dim3(CNT), blk, 0, stream>>>(sbuf, nullptr, nullptr, nullptr,
                                               lnfgg, lnfgb, bufS, nullptr);

    // attention column sums (banded)
    k_zero<<<dim3(64), blk, 0, stream>>>(wcol, CB * CH * CS);
    k_attn<<<dim3(CB * CH, CS / 64), blk, 0, stream>>>(qlnb, klnb, mask, wcol);
    k_scale_v<<<dim3(4096), blk, 0, stream>>>(vb, wcol, attb);

    // output projection (split-K=2, 128x64 tiles -> 1024 blocks) + LN2 (+bo)
    k_gemm_bt<64, 0, 2><<<dim3(32, 16, 2), blk, 0, stream>>>(
        attb, Wob, P0, nullptr, nullptr, nullptr, nullptr, nullptr, CD, CD);
    k_ln_row<0><<<dim3(CNT), blk, 0, stream>>>(P0, P1, nullptr, bo, ln2g, ln2b, nullptr, hb);

    // h_f path + gate
    k_gemm_bt<64, 0, 2><<<dim3(32, 16, 2), blk, 0, stream>>>(
        hb, Whb, P0, nullptr, nullptr, nullptr, nullptr, nullptr, CD, CD);
    k_ln_row<2><<<dim3(CNT), blk, 0, stream>>>(bufS, P0, P1, bf_, lnfgg, lnfgb, bufG, gb);

    // FFN + residual + final LN (+bp2)
    k_gemm_bt<128, 3, 1><<<dim3(32, 32, 1), blk, 0, stream>>>(
        gb, Wp1b, nullptr, ff1b, bp1, nullptr, nullptr, nullptr, CDFF, CD);
    k_gemm_bt<64, 0, 2><<<dim3(32, 16, 2), blk, 0, stream>>>(
        ff1b, Wp2b, P0, nullptr, nullptr, nullptr, nullptr, nullptr, CD, CDFF);
    k_ln_row<3><<<dim3(CNT), blk, 0, stream>>>(P0, P1, bufG, bp2, lnffg, lnffb, out, nullptr);

    (void)in_sizes; (void)n_in; (void)out_size; (void)ws_size;
}

// Round 4
// 362.108 us; speedup vs baseline: 1.9189x; 1.0522x over previous
//
#include <hip/hip_runtime.h>

// ---------------- problem constants ----------------
constexpr int CB   = 4;
constexpr int CS   = 1024;
constexpr int CD   = 1024;
constexpr int CH   = 16;
constexpr int CDFF = 4096;
constexpr int CNT  = CB * CS;   // 4096 tokens

typedef unsigned short ush;
typedef __bf16 bf16_t;
typedef bf16_t bf16x8 __attribute__((ext_vector_type(8)));
typedef float  f32x4  __attribute__((ext_vector_type(4)));

__device__ __forceinline__ ush f2bf(float f) {
    union { float f; unsigned u; } v; v.f = f;
    unsigned u = v.u;
    return (ush)((u + 0x7fffu + ((u >> 16) & 1u)) >> 16);
}
__device__ __forceinline__ float bf2f(ush h) {
    union { unsigned u; float f; } v; v.u = ((unsigned)h) << 16;
    return v.f;
}

// async global->LDS, 16B per lane (dest = wave-uniform base + lane*16)
__device__ __forceinline__ void gll16(const void* g, void* l) {
    __builtin_amdgcn_global_load_lds((const __attribute__((address_space(1))) void*)g,
                                     (__attribute__((address_space(3))) void*)l,
                                     16, 0, 0);
}

// ---------------- fused conversions (x + all weights) + wcol zero ----------------
// arena (elements): [Wq 1M | Wk 1M | Wv 1M | Ws 1M | Wo 1M | Wh 1M | Wp1 4M | Wp2 4M]
constexpr int Q4 = (CD * CD) / 4;
__global__ __launch_bounds__(256) void k_convert_all(
        const float4* __restrict__ Wq, const float4* __restrict__ Wk,
        const float4* __restrict__ Wv, const float4* __restrict__ Ws,
        const float4* __restrict__ Wo, const float4* __restrict__ Wh,
        const float4* __restrict__ Wp1, const float4* __restrict__ Wp2,
        const float4* __restrict__ x, ushort4* __restrict__ arena,
        ushort4* __restrict__ xb, float4* __restrict__ wz) {
    int i = blockIdx.x * 256 + threadIdx.x;
    int stride = gridDim.x * 256;
    for (int i2 = i; i2 < (CB * CH * CS) / 4; i2 += stride)
        wz[i2] = (float4){0.f, 0.f, 0.f, 0.f};
    for (; i < 18 * Q4; i += stride) {
        const float4* src; int off; ushort4* dst;
        if (i < 4 * Q4) {
            if (i < 2 * Q4) { if (i < Q4)     { src = Wq; off = i; }          else { src = Wk; off = i - Q4; } }
            else            { if (i < 3 * Q4) { src = Wv; off = i - 2 * Q4; } else { src = Ws; off = i - 3 * Q4; } }
            dst = arena + i;
        } else if (i < 6 * Q4) {
            if (i < 5 * Q4) { src = Wo; off = i - 4 * Q4; } else { src = Wh; off = i - 5 * Q4; }
            dst = arena + i;
        } else if (i < 14 * Q4) {
            if (i < 10 * Q4) { src = Wp1; off = i - 6 * Q4; } else { src = Wp2; off = i - 10 * Q4; }
            dst = arena + i;
        } else {
            src = x; off = i - 14 * Q4; dst = xb + off;
        }
        float4 v = src[off];
        ushort4 o;
        o.x = f2bf(v.x); o.y = f2bf(v.y); o.z = f2bf(v.z); o.w = f2bf(v.w);
        *dst = o;
    }
}

// ---------------- bf16 MFMA GEMM: C[M,N] = A[M,K]*B[N,K]^T ----------------
// BK=64, XOR-swizzled LDS (conflict-free gll16 writes AND b128 frag reads).
// EPI 0: bf16 partial out (split-K slices stacked at z*M*N, summed in LN).
// EPI 3: +bias relu bf16 out. EPI 4: QKVS fused per-head-LN epilogue.
template <int TN, int EPI, int SPLITK>
__global__ __launch_bounds__(256, 4) void k_gemm_bt(
        const ush* __restrict__ A, const ush* __restrict__ Bm,
        ush* __restrict__ Cb,
        const float* __restrict__ bias, const float* __restrict__ bias2,
        ush* __restrict__ out2, ush* __restrict__ out3, ush* __restrict__ sb,
        int N, int K) {
    constexpr int NJ  = TN / 32;
    constexpr int BCH = TN / 32;
    __shared__ ush As[128 * 64];
    __shared__ ush Bs[TN * 64];
    const int tid  = threadIdx.x;
    const int wave = tid >> 6, lane = tid & 63;
    const int quad = lane >> 4, r = lane & 15;
    const int wm = wave >> 1, wn = wave & 1;
    const int bm = blockIdx.x, bn = blockIdx.y;

    const int kcnt  = K / SPLITK;
    const int kbase = blockIdx.z * kcnt;
    ush* dst0 = Cb;
    if (SPLITK > 1) dst0 += (size_t)blockIdx.z * (size_t)gridDim.x * 128 * N;

    const int trow = tid >> 3, tk8 = tid & 7;
    const int kcl  = tk8 ^ (trow & 7);
    const ush* ap = A  + (size_t)(bm * 128 + trow) * K + kbase + kcl * 8;
    const ush* bp = Bm + (size_t)(bn * TN  + trow) * K + kbase + kcl * 8;
    ush* asd = As + tid * 8;
    ush* bsd = Bs + tid * 8;
    const size_t cstep = (size_t)32 * K;

    f32x4 acc[4][NJ];
#pragma unroll
    for (int i = 0; i < 4; i++)
#pragma unroll
        for (int j = 0; j < NJ; j++) acc[i][j] = (f32x4){0.f, 0.f, 0.f, 0.f};

    const int rx = r & 7;
    for (int k0 = 0; k0 < kcnt; k0 += 64) {
#pragma unroll
        for (int c = 0; c < 4; c++)   gll16(ap + c * cstep, asd + c * 2048);
#pragma unroll
        for (int c = 0; c < BCH; c++) gll16(bp + c * cstep, bsd + c * 2048);
        ap += 64; bp += 64;
        __syncthreads();
#pragma unroll
        for (int h = 0; h < 2; h++) {
            const int kx = (((h << 2) | quad) ^ rx) * 8;
            bf16x8 af[4], bfv[NJ];
#pragma unroll
            for (int i = 0; i < 4; i++)
                af[i] = *(const bf16x8*)(As + (wm * 64 + i * 16 + r) * 64 + kx);
#pragma unroll
            for (int j = 0; j < NJ; j++)
                bfv[j] = *(const bf16x8*)(Bs + (wn * (TN / 2) + j * 16 + r) * 64 + kx);
#pragma unroll
            for (int i = 0; i < 4; i++)
#pragma unroll
                for (int j = 0; j < NJ; j++)
                    acc[i][j] = __builtin_amdgcn_mfma_f32_16x16x32_bf16(af[i], bfv[j], acc[i][j], 0, 0, 0);
        }
        __syncthreads();
    }

    if (EPI == 4) {
        // bn<8 -> q, <16 -> k, <24 -> v (per-head LN -> bf16); >=24 -> s raw bf16
        if (bn >= 24) {
            const int colb = (bn - 24) * 128 + wn * 64;
#pragma unroll
            for (int i = 0; i < 4; i++) {
                const int row0 = bm * 128 + wm * 64 + i * 16 + quad * 4;
#pragma unroll
                for (int j = 0; j < NJ; j++) {
                    const int col = colb + j * 16 + r;
#pragma unroll
                    for (int g = 0; g < 4; g++)
                        sb[(size_t)(row0 + g) * 1024 + col] = f2bf(acc[i][j][g]);
                }
            }
        } else {
            float g4[4], b4[4];
#pragma unroll
            for (int j = 0; j < 4; j++) { g4[j] = bias[j * 16 + r]; b4[j] = bias2[j * 16 + r]; }
            ush* dst; int cb0 = bn * 128 + wn * 64;
            if (bn < 8)       dst = Cb;
            else if (bn < 16) { dst = out2; cb0 -= 1024; }
            else              { dst = out3; cb0 -= 2048; }
#pragma unroll
            for (int i = 0; i < 4; i++) {
                const int row0 = bm * 128 + wm * 64 + i * 16 + quad * 4;
#pragma unroll
                for (int g = 0; g < 4; g++) {
                    float s = 0.f, q = 0.f;
#pragma unroll
                    for (int j = 0; j < 4; j++) { float v = acc[i][j][g]; s += v; q += v * v; }
                    s += __shfl_xor(s, 1); q += __shfl_xor(q, 1);
                    s += __shfl_xor(s, 2); q += __shfl_xor(q, 2);
                    s += __shfl_xor(s, 4); q += __shfl_xor(q, 4);
                    s += __shfl_xor(s, 8); q += __shfl_xor(q, 8);
                    float mu   = s * (1.f / 64.f);
                    float rstd = rsqrtf(q * (1.f / 64.f) - mu * mu + 1e-5f);
#pragma unroll
                    for (int j = 0; j < 4; j++) {
                        float y = (acc[i][j][g] - mu) * rstd * g4[j] + b4[j];
                        dst[(size_t)(row0 + g) * 1024 + cb0 + j * 16 + r] = f2bf(y);
                    }
                }
            }
        }
    } else {
#pragma unroll
        for (int i = 0; i < 4; i++) {
            const int row0 = bm * 128 + wm * 64 + i * 16 + quad * 4;
#pragma unroll
            for (int j = 0; j < NJ; j++) {
                const int col = bn * TN + wn * (TN / 2) + j * 16 + r;
                float bv = (EPI == 3) ? bias[col] : 0.f;
#pragma unroll
                for (int g = 0; g < 4; g++) {
                    float v = acc[i][j][g] + bv;
                    size_t off = (size_t)(row0 + g) * N + col;
                    if (EPI == 3) v = fmaxf(v, 0.f);
                    dst0[off] = f2bf(v);
                }
            }
        }
    }
}

// ---------------- banded attention column-sum kernel ----------------
// wcol[b,h,l] = sum_q softmax_row_q(pre)[l]; exp(pre-8)==0 in fp32 for |q-l|>~104,
// so 3 K-tiles of 64 suffice. All-masked row q=0 adds uniform 1/1024 in k_scale_v.
__global__ __launch_bounds__(256) void k_attn(const ush* __restrict__ qb,
                                              const ush* __restrict__ kb,
                                              const float* __restrict__ mask,
                                              float* __restrict__ wcol) {
    __shared__ ush   Qs[64][72];
    __shared__ ush   Ks[64][72];
    __shared__ float colpart[4][64];

    const int tid  = threadIdx.x;
    const int wave = tid >> 6, lane = tid & 63;
    const int quad = lane >> 4, r = lane & 15;
    const int bh = blockIdx.x, bi = bh >> 4, hi = bh & 15;
    const int q0 = blockIdx.y * 64;

    {
        int row = tid >> 2, seg = (tid & 3) * 16;
        const ush* src = qb + ((size_t)(bi * CS + q0 + row) * CD + hi * 64 + seg);
        *(uint4*)&Qs[row][seg]     = *(const uint4*)src;
        *(uint4*)&Qs[row][seg + 8] = *(const uint4*)(src + 8);
    }
    __syncthreads();
    bf16x8 af0 = *(const bf16x8*)&Qs[wave * 16 + r][quad * 8];
    bf16x8 af1 = *(const bf16x8*)&Qs[wave * 16 + r][32 + quad * 8];

    float mq[4];
#pragma unroll
    for (int g = 0; g < 4; g++) mq[g] = mask[bi * CS + q0 + wave * 16 + quad * 4 + g];

    const int t0 = (q0 >= 128) ? 0 : ((q0 >= 64) ? 1 : 2);
    float pr[3][4][4];
    float s_loc[4] = {0.f, 0.f, 0.f, 0.f};

    for (int t = t0; t < 3; t++) {
        const int l0 = q0 - 128 + t * 64;
        __syncthreads();
        {
            int row = tid >> 2, seg = (tid & 3) * 16;
            const ush* src = kb + ((size_t)(bi * CS + l0 + row) * CD + hi * 64 + seg);
            *(uint4*)&Ks[row][seg]     = *(const uint4*)src;
            *(uint4*)&Ks[row][seg + 8] = *(const uint4*)(src + 8);
        }
        __syncthreads();
#pragma unroll
        for (int jt = 0; jt < 4; jt++) {
            bf16x8 bf0 = *(const bf16x8*)&Ks[jt * 16 + r][quad * 8];
            bf16x8 bf1 = *(const bf16x8*)&Ks[jt * 16 + r][32 + quad * 8];
            f32x4 sc = (f32x4){0.f, 0.f, 0.f, 0.f};
            sc = __builtin_amdgcn_mfma_f32_16x16x32_bf16(af0, bf0, sc, 0, 0, 0);
            sc = __builtin_amdgcn_mfma_f32_16x16x32_bf16(af1, bf1, sc, 0, 0, 0);
            const int l = l0 + jt * 16 + r;
            const float ml = mask[bi * CS + l];
#pragma unroll
            for (int g = 0; g < 4; g++) {
                const int qg = q0 + wave * 16 + quad * 4 + g;
                float e  = sc[g] * 0.03125f;
                float mv = (qg > l) ? 0.f : mq[g] * ml * (-1e20f);
                float p  = __expf(e + mv - fabsf((float)(qg - l)) - 8.f);
                pr[t][jt][g] = p;
                s_loc[g] += p;
            }
        }
    }

    float rs[4];
#pragma unroll
    for (int g = 0; g < 4; g++) {
        float s = s_loc[g];
        s += __shfl_xor(s, 1); s += __shfl_xor(s, 2);
        s += __shfl_xor(s, 4); s += __shfl_xor(s, 8);
        rs[g] = (s > 0.f) ? 1.f / s : 0.f;
    }

    for (int t = t0; t < 3; t++) {
        const int l0 = q0 - 128 + t * 64;
#pragma unroll
        for (int jt = 0; jt < 4; jt++) {
            float csum = 0.f;
#pragma unroll
            for (int g = 0; g < 4; g++) csum += pr[t][jt][g] * rs[g];
            csum += __shfl_xor(csum, 16);
            csum += __shfl_xor(csum, 32);
            if (quad == 0) colpart[wave][jt * 16 + r] = csum;
        }
        __syncthreads();
        if (tid < 64) {
            float v = colpart[0][tid] + colpart[1][tid] + colpart[2][tid] + colpart[3][tid];
            atomicAdd(&wcol[(size_t)bh * CS + l0 + tid], v);
        }
        __syncthreads();
    }
}

// ---------------- scale v by column weights (+ uniform row-0 term) ----------------
__global__ __launch_bounds__(256) void k_scale_v(const ush* __restrict__ vb,
                                                 const float* __restrict__ wcol,
                                                 ush* __restrict__ out) {
    int i = blockIdx.x * 256 + threadIdx.x;
    int stride = gridDim.x * 256;
    for (; i < CNT * CD; i += stride) {
        int token = i >> 10;
        int c = i & (CD - 1);
        int l = token & (CS - 1);
        int b = token >> 10;
        int h = c >> 6;
        float w = wcol[(size_t)(b * CH + h) * CS + l] + (1.f / 1024.f);
        out[i] = f2bf(w * bf2f(vb[i]));
    }
}

// ---------------- row layernorm over D=1024 (bf16 inputs), fused variants ----------------
// MODE 0: LN(b0+b1+badd) -> bf16                        (Wo partials + bo)
// MODE 2: sf=LN(b0); hf=LN(b1+b2); f=sigmoid(sf+hf+badd); LN(f*sf+(1-f)*hf) -> bf16
// MODE 3: LN(b0+b1+b2+badd) -> f32                      (FFN2 partials + g + bp2)
__device__ __forceinline__ void blk_stats(float s, float q, float* red,
                                          int wave, int lane, float& mu, float& rstd) {
#pragma unroll
    for (int off = 32; off >= 1; off >>= 1) {
        s += __shfl_xor(s, off);
        q += __shfl_xor(q, off);
    }
    if (lane == 0) { red[wave] = s; red[4 + wave] = q; }
    __syncthreads();
    s = red[0] + red[1] + red[2] + red[3];
    q = red[4] + red[5] + red[6] + red[7];
    mu = s * (1.f / 1024.f);
    rstd = rsqrtf(q * (1.f / 1024.f) - mu * mu + 1e-5f);
    __syncthreads();
}

template <int MODE>
__global__ __launch_bounds__(256) void k_ln_row(const ush* __restrict__ b0,
                                                const ush* __restrict__ b1,
                                                const ush* __restrict__ b2,
                                                const float* __restrict__ badd,
                                                const float* __restrict__ gam,
                                                const float* __restrict__ bet,
                                                float* __restrict__ outf,
                                                ush* __restrict__ outb) {
    __shared__ float red[8];
    const int tid = threadIdx.x, wave = tid >> 6, lane = tid & 63;
    const size_t base = (size_t)blockIdx.x * CD;
    float t[4], sr[4];
    float s = 0.f, q = 0.f, mu, rstd;

    if (MODE == 2) {
#pragma unroll
        for (int j = 0; j < 4; j++) {
            int col = tid + j * 256;
            sr[j] = bf2f(b0[base + col]);
            t[j]  = bf2f(b1[base + col]) + bf2f(b2[base + col]);
        }
        // stats over s_raw
#pragma unroll
        for (int j = 0; j < 4; j++) { s += sr[j]; q += sr[j] * sr[j]; }
        blk_stats(s, q, red, wave, lane, mu, rstd);
#pragma unroll
        for (int j = 0; j < 4; j++) {
            int col = tid + j * 256;
            sr[j] = (sr[j] - mu) * rstd * gam[col] + bet[col];   // s_f
        }
        // stats over h_raw
        s = 0.f; q = 0.f;
#pragma unroll
        for (int j = 0; j < 4; j++) { s += t[j]; q += t[j] * t[j]; }
        blk_stats(s, q, red, wave, lane, mu, rstd);
#pragma unroll
        for (int j = 0; j < 4; j++) {
            int col = tid + j * 256;
            float hf = (t[j] - mu) * rstd * gam[col] + bet[col];
            float f  = 1.f / (1.f + __expf(-(sr[j] + hf + badd[col])));
            t[j] = f * sr[j] + (1.f - f) * hf;
        }
    } else {
#pragma unroll
        for (int j = 0; j < 4; j++) {
            int col = tid + j * 256;
            if (MODE == 0) t[j] = bf2f(b0[base + col]) + bf2f(b1[base + col]) + badd[col];
            else           t[j] = bf2f(b0[base + col]) + bf2f(b1[base + col]) + bf2f(b2[base + col]) + badd[col];
        }
    }

    s = 0.f; q = 0.f;
#pragma unroll
    for (int j = 0; j < 4; j++) { s += t[j]; q += t[j] * t[j]; }
    blk_stats(s, q, red, wave, lane, mu, rstd);

#pragma unroll
    for (int j = 0; j < 4; j++) {
        int col = tid + j * 256;
        float y = (t[j] - mu) * rstd * gam[col] + bet[col];
        if (MODE == 3) outf[base + col] = y;
        else           outb[base + col] = f2bf(y);
    }
}

// ---------------- host launch ----------------
extern "C" void kernel_launch(void* const* d_in, const int* in_sizes, int n_in,
                              void* d_out, int out_size, void* d_ws, size_t ws_size,
                              hipStream_t stream) {
    const float* x    = (const float*)d_in[0];
    const float* mask = (const float*)d_in[1];
    const float* Wq   = (const float*)d_in[2];
    const float* Wk   = (const float*)d_in[3];
    const float* Wv   = (const float*)d_in[4];
    const float* ln1g = (const float*)d_in[5];
    const float* ln1b = (const float*)d_in[6];
    const float* Wo   = (const float*)d_in[7];
    const float* bo   = (const float*)d_in[8];
    const float* ln2g = (const float*)d_in[9];
    const float* ln2b = (const float*)d_in[10];
    const float* Ws   = (const float*)d_in[11];
    const float* Wh   = (const float*)d_in[12];
    const float* bf_  = (const float*)d_in[13];
    const float* lnfgg = (const float*)d_in[14];
    const float* lnfgb = (const float*)d_in[15];
    const float* Wp1  = (const float*)d_in[16];
    const float* bp1  = (const float*)d_in[17];
    const float* Wp2  = (const float*)d_in[18];
    const float* bp2  = (const float*)d_in[19];
    const float* lnffg = (const float*)d_in[20];
    const float* lnffb = (const float*)d_in[21];
    float* out = (float*)d_out;

    char* p = (char*)d_ws;
    auto alloc = [&](size_t bytes) -> char* {
        char* r = p;
        p += (bytes + 255) & ~(size_t)255;
        return r;
    };
    ush*   arena = (ush*)alloc((size_t)14 * CD * CD * 2);  // 28 MB
    ush*   Wob   = arena + (size_t)4 * CD * CD;
    ush*   Whb   = arena + (size_t)5 * CD * CD;
    ush*   Wp1b  = arena + (size_t)6 * CD * CD;
    ush*   Wp2b  = arena + (size_t)10 * CD * CD;
    ush*   xb    = (ush*)alloc((size_t)CNT * CD * 2);      // 8 MB
    ush*   klnb  = (ush*)alloc((size_t)CNT * CD * 2);      // 8 MB (hb alias)
    ush*   vb    = (ush*)alloc((size_t)CNT * CD * 2);      // 8 MB
    ush*   qlnb  = (ush*)alloc((size_t)CNT * CD * 2);      // 8 MB (attb alias)
    ush*   gb    = (ush*)alloc((size_t)CNT * CD * 2);      // 8 MB
    ush*   P     = (ush*)alloc((size_t)2 * CNT * CD * 2);  // 16 MB split-K bf16 partials
    ush*   P1    = P + (size_t)CNT * CD;
    ush*   ff1b  = (ush*)alloc((size_t)CNT * CDFF * 2);    // 32 MB (sbuf aliases front)
    float* wcol  = (float*)alloc((size_t)CB * CH * CS * 4);
    ush*   sbuf  = ff1b;           // s raw bf16; consumed by gate LN before FFN1 writes
    ush*   attb  = qlnb;           // q-ln consumed by k_attn before k_scale_v writes
    ush*   hb    = klnb;           // k-ln consumed by k_attn before ln_row<0> writes

    dim3 blk(256);

    k_convert_all<<<dim3(8192), blk, 0, stream>>>(
        (const float4*)Wq, (const float4*)Wk, (const float4*)Wv, (const float4*)Ws,
        (const float4*)Wo, (const float4*)Wh, (const float4*)Wp1, (const float4*)Wp2,
        (const float4*)x, (ushort4*)arena, (ushort4*)xb, (float4*)wcol);

    // fused QKVS projection: q,k,v per-head-LN -> bf16; s raw -> bf16
    k_gemm_bt<128, 4, 1><<<dim3(32, 32, 1), blk, 0, stream>>>(
        xb, arena, qlnb, ln1g, ln1b, klnb, vb, sbuf, 4096, CD);

    // attention column sums (banded)
    k_attn<<<dim3(CB * CH, CS / 64), blk, 0, stream>>>(qlnb, klnb, mask, wcol);
    k_scale_v<<<dim3(4096), blk, 0, stream>>>(vb, wcol, attb);

    // output projection (split-K=2 bf16 partials) + LN2 (+bo)
    k_gemm_bt<64, 0, 2><<<dim3(32, 16, 2), blk, 0, stream>>>(
        attb, Wob, P, nullptr, nullptr, nullptr, nullptr, nullptr, CD, CD);
    k_ln_row<0><<<dim3(CNT), blk, 0, stream>>>(P, P1, nullptr, bo, ln2g, ln2b, nullptr, hb);

    // h_f path + gate (s_f LN fused here)
    k_gemm_bt<64, 0, 2><<<dim3(32, 16, 2), blk, 0, stream>>>(
        hb, Whb, P, nullptr, nullptr, nullptr, nullptr, nullptr, CD, CD);
    k_ln_row<2><<<dim3(CNT), blk, 0, stream>>>(sbuf, P, P1, bf_, lnfgg, lnfgb, nullptr, gb);

    // FFN + residual (g as bf16) + final LN (+bp2)
    k_gemm_bt<128, 3, 1><<<dim3(32, 32, 1), blk, 0, stream>>>(
        gb, Wp1b, ff1b, bp1, nullptr, nullptr, nullptr, nullptr, CDFF, CD);
    k_gemm_bt<64, 0, 2><<<dim3(32, 16, 2), blk, 0, stream>>>(
        ff1b, Wp2b, P, nullptr, nullptr, nullptr, nullptr, nullptr, CD, CDFF);
    k_ln_row<3><<<dim3(CNT), blk, 0, stream>>>(P, P1, gb, bp2, lnffg, lnffb, out, nullptr);

    (void)in_sizes; (void)n_in; (void)out_size; (void)ws_size;
}

// Round 5
// 359.745 us; speedup vs baseline: 1.9316x; 1.0066x over previous
//
#include <hip/hip_runtime.h>

// ---------------- problem constants ----------------
constexpr int CB   = 4;
constexpr int CS   = 1024;
constexpr int CD   = 1024;
constexpr int CH   = 16;
constexpr int CDFF = 4096;
constexpr int CNT  = CB * CS;   // 4096 tokens

typedef unsigned short ush;
typedef __bf16 bf16_t;
typedef bf16_t bf16x8 __attribute__((ext_vector_type(8)));
typedef float  f32x4  __attribute__((ext_vector_type(4)));

__device__ __forceinline__ ush f2bf(float f) {
    union { float f; unsigned u; } v; v.f = f;
    unsigned u = v.u;
    return (ush)((u + 0x7fffu + ((u >> 16) & 1u)) >> 16);
}
__device__ __forceinline__ float bf2f(ush h) {
    union { unsigned u; float f; } v; v.u = ((unsigned)h) << 16;
    return v.f;
}

// async global->LDS, 16B per lane (dest = wave-uniform base + lane*16)
__device__ __forceinline__ void gll16(const void* g, void* l) {
    __builtin_amdgcn_global_load_lds((const __attribute__((address_space(1))) void*)g,
                                     (__attribute__((address_space(3))) void*)l,
                                     16, 0, 0);
}

// ---------------- fused conversions (x + all weights) + wcol zero ----------------
// arena (elements): [Wq 1M | Wk 1M | Wv 1M | Ws 1M | Wo 1M | Wh 1M | Wp1 4M | Wp2 4M]
constexpr int Q4 = (CD * CD) / 4;
__global__ __launch_bounds__(256) void k_convert_all(
        const float4* __restrict__ Wq, const float4* __restrict__ Wk,
        const float4* __restrict__ Wv, const float4* __restrict__ Ws,
        const float4* __restrict__ Wo, const float4* __restrict__ Wh,
        const float4* __restrict__ Wp1, const float4* __restrict__ Wp2,
        const float4* __restrict__ x, ushort4* __restrict__ arena,
        ushort4* __restrict__ xb, float4* __restrict__ wz) {
    int i = blockIdx.x * 256 + threadIdx.x;
    int stride = gridDim.x * 256;
    for (int i2 = i; i2 < (CB * CH * CS) / 4; i2 += stride)
        wz[i2] = (float4){0.f, 0.f, 0.f, 0.f};
    for (; i < 18 * Q4; i += stride) {
        const float4* src; int off; ushort4* dst;
        if (i < 4 * Q4) {
            if (i < 2 * Q4) { if (i < Q4)     { src = Wq; off = i; }          else { src = Wk; off = i - Q4; } }
            else            { if (i < 3 * Q4) { src = Wv; off = i - 2 * Q4; } else { src = Ws; off = i - 3 * Q4; } }
            dst = arena + i;
        } else if (i < 6 * Q4) {
            if (i < 5 * Q4) { src = Wo; off = i - 4 * Q4; } else { src = Wh; off = i - 5 * Q4; }
            dst = arena + i;
        } else if (i < 14 * Q4) {
            if (i < 10 * Q4) { src = Wp1; off = i - 6 * Q4; } else { src = Wp2; off = i - 10 * Q4; }
            dst = arena + i;
        } else {
            src = x; off = i - 14 * Q4; dst = xb + off;
        }
        float4 v = src[off];
        ushort4 o;
        o.x = f2bf(v.x); o.y = f2bf(v.y); o.z = f2bf(v.z); o.w = f2bf(v.w);
        *dst = o;
    }
}

// ---------------- bf16 MFMA GEMM: C[M,N] = A[M,K]*B[N,K]^T ----------------
// BK=64, XOR-swizzled LDS staging (conflict-free gll16 writes AND b128 frag reads).
// Epilogue: LDS-staged transpose -> full-line global_store_dwordx4 (no RMW fetch).
// EPI 0: bf16 partial out (split-K slices stacked at z*M*N, summed in LN).
// EPI 3: +bias relu bf16 out. EPI 4: QKVS fused per-head-LN epilogue.
template <int TN, int EPI, int SPLITK>
__global__ __launch_bounds__(256, 4) void k_gemm_bt(
        const ush* __restrict__ A, const ush* __restrict__ Bm,
        ush* __restrict__ Cb,
        const float* __restrict__ bias, const float* __restrict__ bias2,
        ush* __restrict__ out2, ush* __restrict__ out3, ush* __restrict__ sb,
        int N, int K) {
    constexpr int NJ  = TN / 32;
    constexpr int BCH = TN / 32;
    constexpr int EPS = TN + 8;                       // epilogue row stride (ush), 16B-aligned rows
    constexpr int STG = (128 + TN) * 64;              // staging ushorts
    constexpr int LDS_USH = (STG > 128 * EPS) ? STG : 128 * EPS;
    __shared__ ush smem[LDS_USH];
    ush* As = smem;
    ush* Bs = smem + 128 * 64;
    ush* Cs = smem;                                   // epilogue reuse

    const int tid  = threadIdx.x;
    const int wave = tid >> 6, lane = tid & 63;
    const int quad = lane >> 4, r = lane & 15;
    const int wm = wave >> 1, wn = wave & 1;
    const int bm = blockIdx.x, bn = blockIdx.y;

    const int kcnt  = K / SPLITK;
    const int kbase = blockIdx.z * kcnt;
    ush* dst0 = Cb;
    if (SPLITK > 1) dst0 += (size_t)blockIdx.z * (size_t)gridDim.x * 128 * N;

    const int trow = tid >> 3, tk8 = tid & 7;
    const int kcl  = tk8 ^ (trow & 7);
    const ush* ap = A  + (size_t)(bm * 128 + trow) * K + kbase + kcl * 8;
    const ush* bp = Bm + (size_t)(bn * TN  + trow) * K + kbase + kcl * 8;
    ush* asd = As + tid * 8;
    ush* bsd = Bs + tid * 8;
    const size_t cstep = (size_t)32 * K;

    f32x4 acc[4][NJ];
#pragma unroll
    for (int i = 0; i < 4; i++)
#pragma unroll
        for (int j = 0; j < NJ; j++) acc[i][j] = (f32x4){0.f, 0.f, 0.f, 0.f};

    const int rx = r & 7;
    for (int k0 = 0; k0 < kcnt; k0 += 64) {
#pragma unroll
        for (int c = 0; c < 4; c++)   gll16(ap + c * cstep, asd + c * 2048);
#pragma unroll
        for (int c = 0; c < BCH; c++) gll16(bp + c * cstep, bsd + c * 2048);
        ap += 64; bp += 64;
        __syncthreads();
#pragma unroll
        for (int h = 0; h < 2; h++) {
            const int kx = (((h << 2) | quad) ^ rx) * 8;
            bf16x8 af[4], bfv[NJ];
#pragma unroll
            for (int i = 0; i < 4; i++)
                af[i] = *(const bf16x8*)(As + (wm * 64 + i * 16 + r) * 64 + kx);
#pragma unroll
            for (int j = 0; j < NJ; j++)
                bfv[j] = *(const bf16x8*)(Bs + (wn * (TN / 2) + j * 16 + r) * 64 + kx);
#pragma unroll
            for (int i = 0; i < 4; i++)
#pragma unroll
                for (int j = 0; j < NJ; j++)
                    acc[i][j] = __builtin_amdgcn_mfma_f32_16x16x32_bf16(af[i], bfv[j], acc[i][j], 0, 0, 0);
        }
        __syncthreads();
    }

    // ---- deposit output tile into LDS (bf16, padded rows) ----
    if (EPI == 4 && bn < 24) {
        // per-head LN (each wave's 64 cols == one head)
        float g4[4], b4[4];
#pragma unroll
        for (int j = 0; j < 4; j++) { g4[j] = bias[j * 16 + r]; b4[j] = bias2[j * 16 + r]; }
#pragma unroll
        for (int i = 0; i < 4; i++) {
            const int row = wm * 64 + i * 16 + quad * 4;
#pragma unroll
            for (int g = 0; g < 4; g++) {
                float s = 0.f, q = 0.f;
#pragma unroll
                for (int j = 0; j < 4; j++) { float v = acc[i][j][g]; s += v; q += v * v; }
                s += __shfl_xor(s, 1); q += __shfl_xor(q, 1);
                s += __shfl_xor(s, 2); q += __shfl_xor(q, 2);
                s += __shfl_xor(s, 4); q += __shfl_xor(q, 4);
                s += __shfl_xor(s, 8); q += __shfl_xor(q, 8);
                float mu   = s * (1.f / 64.f);
                float rstd = rsqrtf(q * (1.f / 64.f) - mu * mu + 1e-5f);
#pragma unroll
                for (int j = 0; j < 4; j++) {
                    float y = (acc[i][j][g] - mu) * rstd * g4[j] + b4[j];
                    Cs[(row + g) * EPS + wn * 64 + j * 16 + r] = f2bf(y);
                }
            }
        }
    } else {
#pragma unroll
        for (int i = 0; i < 4; i++) {
            const int row = wm * 64 + i * 16 + quad * 4;
#pragma unroll
            for (int j = 0; j < NJ; j++) {
                const int col = wn * (TN / 2) + j * 16 + r;
                float bv = (EPI == 3) ? bias[bn * TN + col] : 0.f;
#pragma unroll
                for (int g = 0; g < 4; g++) {
                    float v = acc[i][j][g] + bv;
                    if (EPI == 3) v = fmaxf(v, 0.f);
                    Cs[(row + g) * EPS + col] = f2bf(v);
                }
            }
        }
    }
    __syncthreads();

    // ---- vectorized store: full 128B-line coverage ----
    ush* dst = dst0;
    int colbase = bn * TN, Nn = N;
    if (EPI == 4) {
        Nn = 1024;
        if (bn < 8)       { dst = Cb;   colbase = bn * 128; }
        else if (bn < 16) { dst = out2; colbase = (bn - 8) * 128; }
        else if (bn < 24) { dst = out3; colbase = (bn - 16) * 128; }
        else              { dst = sb;   colbase = (bn - 24) * 128; }
    }
    const int tpr = TN / 8;                 // threads per row
    const int rpp = 2048 / TN;              // rows per pass
    const int srow2 = tid / tpr;
    const int scol2 = (tid % tpr) * 8;
#pragma unroll
    for (int pp = 0; pp < TN / 16; pp++) {
        const int rr = pp * rpp + srow2;
        uint4 vv = *(const uint4*)&Cs[rr * EPS + scol2];
        *(uint4*)&dst[(size_t)(bm * 128 + rr) * Nn + colbase + scol2] = vv;
    }
}

// ---------------- banded attention column-sum kernel ----------------
// wcol[b,h,l] = sum_q softmax_row_q(pre)[l]; exp(pre-8)==0 in fp32 for |q-l|>~104,
// so 3 K-tiles of 64 suffice. All-masked row q=0 adds uniform 1/1024 in k_scale_v.
__global__ __launch_bounds__(256) void k_attn(const ush* __restrict__ qb,
                                              const ush* __restrict__ kb,
                                              const float* __restrict__ mask,
                                              float* __restrict__ wcol) {
    __shared__ ush   Qs[64][72];
    __shared__ ush   Ks[64][72];
    __shared__ float colpart[4][64];

    const int tid  = threadIdx.x;
    const int wave = tid >> 6, lane = tid & 63;
    const int quad = lane >> 4, r = lane & 15;
    const int bh = blockIdx.x, bi = bh >> 4, hi = bh & 15;
    const int q0 = blockIdx.y * 64;

    {
        int row = tid >> 2, seg = (tid & 3) * 16;
        const ush* src = qb + ((size_t)(bi * CS + q0 + row) * CD + hi * 64 + seg);
        *(uint4*)&Qs[row][seg]     = *(const uint4*)src;
        *(uint4*)&Qs[row][seg + 8] = *(const uint4*)(src + 8);
    }
    __syncthreads();
    bf16x8 af0 = *(const bf16x8*)&Qs[wave * 16 + r][quad * 8];
    bf16x8 af1 = *(const bf16x8*)&Qs[wave * 16 + r][32 + quad * 8];

    float mq[4];
#pragma unroll
    for (int g = 0; g < 4; g++) mq[g] = mask[bi * CS + q0 + wave * 16 + quad * 4 + g];

    const int t0 = (q0 >= 128) ? 0 : ((q0 >= 64) ? 1 : 2);
    float pr[3][4][4];
    float s_loc[4] = {0.f, 0.f, 0.f, 0.f};

    for (int t = t0; t < 3; t++) {
        const int l0 = q0 - 128 + t * 64;
        __syncthreads();
        {
            int row = tid >> 2, seg = (tid & 3) * 16;
            const ush* src = kb + ((size_t)(bi * CS + l0 + row) * CD + hi * 64 + seg);
            *(uint4*)&Ks[row][seg]     = *(const uint4*)src;
            *(uint4*)&Ks[row][seg + 8] = *(const uint4*)(src + 8);
        }
        __syncthreads();
#pragma unroll
        for (int jt = 0; jt < 4; jt++) {
            bf16x8 bf0 = *(const bf16x8*)&Ks[jt * 16 + r][quad * 8];
            bf16x8 bf1 = *(const bf16x8*)&Ks[jt * 16 + r][32 + quad * 8];
            f32x4 sc = (f32x4){0.f, 0.f, 0.f, 0.f};
            sc = __builtin_amdgcn_mfma_f32_16x16x32_bf16(af0, bf0, sc, 0, 0, 0);
            sc = __builtin_amdgcn_mfma_f32_16x16x32_bf16(af1, bf1, sc, 0, 0, 0);
            const int l = l0 + jt * 16 + r;
            const float ml = mask[bi * CS + l];
#pragma unroll
            for (int g = 0; g < 4; g++) {
                const int qg = q0 + wave * 16 + quad * 4 + g;
                float e  = sc[g] * 0.03125f;
                float mv = (qg > l) ? 0.f : mq[g] * ml * (-1e20f);
                float p  = __expf(e + mv - fabsf((float)(qg - l)) - 8.f);
                pr[t][jt][g] = p;
                s_loc[g] += p;
            }
        }
    }

    float rs[4];
#pragma unroll
    for (int g = 0; g < 4; g++) {
        float s = s_loc[g];
        s += __shfl_xor(s, 1); s += __shfl_xor(s, 2);
        s += __shfl_xor(s, 4); s += __shfl_xor(s, 8);
        rs[g] = (s > 0.f) ? 1.f / s : 0.f;
    }

    for (int t = t0; t < 3; t++) {
        const int l0 = q0 - 128 + t * 64;
#pragma unroll
        for (int jt = 0; jt < 4; jt++) {
            float csum = 0.f;
#pragma unroll
            for (int g = 0; g < 4; g++) csum += pr[t][jt][g] * rs[g];
            csum += __shfl_xor(csum, 16);
            csum += __shfl_xor(csum, 32);
            if (quad == 0) colpart[wave][jt * 16 + r] = csum;
        }
        __syncthreads();
        if (tid < 64) {
            float v = colpart[0][tid] + colpart[1][tid] + colpart[2][tid] + colpart[3][tid];
            atomicAdd(&wcol[(size_t)bh * CS + l0 + tid], v);
        }
        __syncthreads();
    }
}

// ---------------- scale v by column weights (+ uniform row-0 term) ----------------
__global__ __launch_bounds__(256) void k_scale_v(const ush* __restrict__ vb,
                                                 const float* __restrict__ wcol,
                                                 ush* __restrict__ out) {
    int i = blockIdx.x * 256 + threadIdx.x;
    int stride = gridDim.x * 256;
    for (; i < CNT * CD; i += stride) {
        int token = i >> 10;
        int c = i & (CD - 1);
        int l = token & (CS - 1);
        int b = token >> 10;
        int h = c >> 6;
        float w = wcol[(size_t)(b * CH + h) * CS + l] + (1.f / 1024.f);
        out[i] = f2bf(w * bf2f(vb[i]));
    }
}

// ---------------- row layernorm over D=1024 (bf16 inputs), fused variants ----------------
// MODE 0: LN(b0+b1+badd) -> bf16                        (Wo partials + bo)
// MODE 2: sf=LN(b0); hf=LN(b1+b2); f=sigmoid(sf+hf+badd); LN(f*sf+(1-f)*hf) -> bf16
// MODE 3: LN(b0+b1+b2+badd) -> f32                      (FFN2 partials + g + bp2)
__device__ __forceinline__ void blk_stats(float s, float q, float* red,
                                          int wave, int lane, float& mu, float& rstd) {
#pragma unroll
    for (int off = 32; off >= 1; off >>= 1) {
        s += __shfl_xor(s, off);
        q += __shfl_xor(q, off);
    }
    if (lane == 0) { red[wave] = s; red[4 + wave] = q; }
    __syncthreads();
    s = red[0] + red[1] + red[2] + red[3];
    q = red[4] + red[5] + red[6] + red[7];
    mu = s * (1.f / 1024.f);
    rstd = rsqrtf(q * (1.f / 1024.f) - mu * mu + 1e-5f);
    __syncthreads();
}

template <int MODE>
__global__ __launch_bounds__(256) void k_ln_row(const ush* __restrict__ b0,
                                                const ush* __restrict__ b1,
                                                const ush* __restrict__ b2,
                                                const float* __restrict__ badd,
                                                const float* __restrict__ gam,
                                                const float* __restrict__ bet,
                                                float* __restrict__ outf,
                                                ush* __restrict__ outb) {
    __shared__ float red[8];
    const int tid = threadIdx.x, wave = tid >> 6, lane = tid & 63;
    const size_t base = (size_t)blockIdx.x * CD;
    float t[4], sr[4];
    float s = 0.f, q = 0.f, mu, rstd;

    if (MODE == 2) {
#pragma unroll
        for (int j = 0; j < 4; j++) {
            int col = tid + j * 256;
            sr[j] = bf2f(b0[base + col]);
            t[j]  = bf2f(b1[base + col]) + bf2f(b2[base + col]);
        }
#pragma unroll
        for (int j = 0; j < 4; j++) { s += sr[j]; q += sr[j] * sr[j]; }
        blk_stats(s, q, red, wave, lane, mu, rstd);
#pragma unroll
        for (int j = 0; j < 4; j++) {
            int col = tid + j * 256;
            sr[j] = (sr[j] - mu) * rstd * gam[col] + bet[col];   // s_f
        }
        s = 0.f; q = 0.f;
#pragma unroll
        for (int j = 0; j < 4; j++) { s += t[j]; q += t[j] * t[j]; }
        blk_stats(s, q, red, wave, lane, mu, rstd);
#pragma unroll
        for (int j = 0; j < 4; j++) {
            int col = tid + j * 256;
            float hf = (t[j] - mu) * rstd * gam[col] + bet[col];
            float f  = 1.f / (1.f + __expf(-(sr[j] + hf + badd[col])));
            t[j] = f * sr[j] + (1.f - f) * hf;
        }
    } else {
#pragma unroll
        for (int j = 0; j < 4; j++) {
            int col = tid + j * 256;
            if (MODE == 0) t[j] = bf2f(b0[base + col]) + bf2f(b1[base + col]) + badd[col];
            else           t[j] = bf2f(b0[base + col]) + bf2f(b1[base + col]) + bf2f(b2[base + col]) + badd[col];
        }
    }

    s = 0.f; q = 0.f;
#pragma unroll
    for (int j = 0; j < 4; j++) { s += t[j]; q += t[j] * t[j]; }
    blk_stats(s, q, red, wave, lane, mu, rstd);

#pragma unroll
    for (int j = 0; j < 4; j++) {
        int col = tid + j * 256;
        float y = (t[j] - mu) * rstd * gam[col] + bet[col];
        if (MODE == 3) outf[base + col] = y;
        else           outb[base + col] = f2bf(y);
    }
}

// ---------------- host launch ----------------
extern "C" void kernel_launch(void* const* d_in, const int* in_sizes, int n_in,
                              void* d_out, int out_size, void* d_ws, size_t ws_size,
                              hipStream_t stream) {
    const float* x    = (const float*)d_in[0];
    const float* mask = (const float*)d_in[1];
    const float* Wq   = (const float*)d_in[2];
    const float* Wk   = (const float*)d_in[3];
    const float* Wv   = (const float*)d_in[4];
    const float* ln1g = (const float*)d_in[5];
    const float* ln1b = (const float*)d_in[6];
    const float* Wo   = (const float*)d_in[7];
    const float* bo   = (const float*)d_in[8];
    const float* ln2g = (const float*)d_in[9];
    const float* ln2b = (const float*)d_in[10];
    const float* Ws   = (const float*)d_in[11];
    const float* Wh   = (const float*)d_in[12];
    const float* bf_  = (const float*)d_in[13];
    const float* lnfgg = (const float*)d_in[14];
    const float* lnfgb = (const float*)d_in[15];
    const float* Wp1  = (const float*)d_in[16];
    const float* bp1  = (const float*)d_in[17];
    const float* Wp2  = (const float*)d_in[18];
    const float* bp2  = (const float*)d_in[19];
    const float* lnffg = (const float*)d_in[20];
    const float* lnffb = (const float*)d_in[21];
    float* out = (float*)d_out;

    char* p = (char*)d_ws;
    auto alloc = [&](size_t bytes) -> char* {
        char* r = p;
        p += (bytes + 255) & ~(size_t)255;
        return r;
    };
    ush*   arena = (ush*)alloc((size_t)14 * CD * CD * 2);  // 28 MB
    ush*   Wob   = arena + (size_t)4 * CD * CD;
    ush*   Whb   = arena + (size_t)5 * CD * CD;
    ush*   Wp1b  = arena + (size_t)6 * CD * CD;
    ush*   Wp2b  = arena + (size_t)10 * CD * CD;
    ush*   xb    = (ush*)alloc((size_t)CNT * CD * 2);      // 8 MB
    ush*   klnb  = (ush*)alloc((size_t)CNT * CD * 2);      // 8 MB (hb alias)
    ush*   vb    = (ush*)alloc((size_t)CNT * CD * 2);      // 8 MB
    ush*   qlnb  = (ush*)alloc((size_t)CNT * CD * 2);      // 8 MB (attb alias)
    ush*   gb    = (ush*)alloc((size_t)CNT * CD * 2);      // 8 MB
    ush*   P     = (ush*)alloc((size_t)2 * CNT * CD * 2);  // 16 MB split-K bf16 partials
    ush*   P1    = P + (size_t)CNT * CD;
    ush*   ff1b  = (ush*)alloc((size_t)CNT * CDFF * 2);    // 32 MB (sbuf aliases front)
    float* wcol  = (float*)alloc((size_t)CB * CH * CS * 4);
    ush*   sbuf  = ff1b;           // s raw bf16; consumed by gate LN before FFN1 writes
    ush*   attb  = qlnb;           // q-ln consumed by k_attn before k_scale_v writes
    ush*   hb    = klnb;           // k-ln consumed by k_attn before ln_row<0> writes

    dim3 blk(256);

    k_convert_all<<<dim3(8192), blk, 0, stream>>>(
        (const float4*)Wq, (const float4*)Wk, (const float4*)Wv, (const float4*)Ws,
        (const float4*)Wo, (const float4*)Wh, (const float4*)Wp1, (const float4*)Wp2,
        (const float4*)x, (ushort4*)arena, (ushort4*)xb, (float4*)wcol);

    // fused QKVS projection: q,k,v per-head-LN -> bf16; s raw -> bf16
    k_gemm_bt<128, 4, 1><<<dim3(32, 32, 1), blk, 0, stream>>>(
        xb, arena, qlnb, ln1g, ln1b, klnb, vb, sbuf, 4096, CD);

    // attention column sums (banded)
    k_attn<<<dim3(CB * CH, CS / 64), blk, 0, stream>>>(qlnb, klnb, mask, wcol);
    k_scale_v<<<dim3(4096), blk, 0, stream>>>(vb, wcol, attb);

    // output projection (split-K=2 bf16 partials) + LN2 (+bo)
    k_gemm_bt<64, 0, 2><<<dim3(32, 16, 2), blk, 0, stream>>>(
        attb, Wob, P, nullptr, nullptr, nullptr, nullptr, nullptr, CD, CD);
    k_ln_row<0><<<dim3(CNT), blk, 0, stream>>>(P, P1, nullptr, bo, ln2g, ln2b, nullptr, hb);

    // h_f path + gate (s_f LN fused here)
    k_gemm_bt<64, 0, 2><<<dim3(32, 16, 2), blk, 0, stream>>>(
        hb, Whb, P, nullptr, nullptr, nullptr, nullptr, nullptr, CD, CD);
    k_ln_row<2><<<dim3(CNT), blk, 0, stream>>>(sbuf, P, P1, bf_, lnfgg, lnfgb, nullptr, gb);

    // FFN + residual (g as bf16) + final LN (+bp2)
    k_gemm_bt<128, 3, 1><<<dim3(32, 32, 1), blk, 0, stream>>>(
        gb, Wp1b, ff1b, bp1, nullptr, nullptr, nullptr, nullptr, CDFF, CD);
    k_gemm_bt<64, 0, 2><<<dim3(32, 16, 2), blk, 0, stream>>>(
        ff1b, Wp2b, P, nullptr, nullptr, nullptr, nullptr, nullptr, CD, CDFF);
    k_ln_row<3><<<dim3(CNT), blk, 0, stream>>>(P, P1, gb, bp2, lnffg, lnffb, out, nullptr);

    (void)in_sizes; (void)n_in; (void)out_size; (void)ws_size;
}

// Round 6
// 355.269 us; speedup vs baseline: 1.9559x; 1.0126x over previous
//
#include <hip/hip_runtime.h>

// ---------------- problem constants ----------------
constexpr int CB   = 4;
constexpr int CS   = 1024;
constexpr int CD   = 1024;
constexpr int CH   = 16;
constexpr int CDFF = 4096;
constexpr int CNT  = CB * CS;   // 4096 tokens

typedef unsigned short ush;
typedef __bf16 bf16_t;
typedef bf16_t bf16x8 __attribute__((ext_vector_type(8)));
typedef float  f32x4  __attribute__((ext_vector_type(4)));

__device__ __forceinline__ ush f2bf(float f) {
    union { float f; unsigned u; } v; v.f = f;
    unsigned u = v.u;
    return (ush)((u + 0x7fffu + ((u >> 16) & 1u)) >> 16);
}
__device__ __forceinline__ float bf2f(ush h) {
    union { unsigned u; float f; } v; v.u = ((unsigned)h) << 16;
    return v.f;
}
__device__ __forceinline__ void ub8(uint4 v, float* d) {
    d[0] = bf2f((ush)v.x); d[1] = bf2f((ush)(v.x >> 16));
    d[2] = bf2f((ush)v.y); d[3] = bf2f((ush)(v.y >> 16));
    d[4] = bf2f((ush)v.z); d[5] = bf2f((ush)(v.z >> 16));
    d[6] = bf2f((ush)v.w); d[7] = bf2f((ush)(v.w >> 16));
}
__device__ __forceinline__ uint4 pb8(const float* d) {
    uint4 v;
    v.x = (unsigned)f2bf(d[0]) | ((unsigned)f2bf(d[1]) << 16);
    v.y = (unsigned)f2bf(d[2]) | ((unsigned)f2bf(d[3]) << 16);
    v.z = (unsigned)f2bf(d[4]) | ((unsigned)f2bf(d[5]) << 16);
    v.w = (unsigned)f2bf(d[6]) | ((unsigned)f2bf(d[7]) << 16);
    return v;
}

// async global->LDS, 16B per lane (dest = wave-uniform base + lane*16)
__device__ __forceinline__ void gll16(const void* g, void* l) {
    __builtin_amdgcn_global_load_lds((const __attribute__((address_space(1))) void*)g,
                                     (__attribute__((address_space(3))) void*)l,
                                     16, 0, 0);
}

// ---------------- fused conversions (x + all weights) + wcol zero ----------------
// arena (elements): [Wq 1M | Wk 1M | Wv 1M | Ws 1M | Wo 1M | Wh 1M | Wp1 4M | Wp2 4M]
constexpr int Q4 = (CD * CD) / 4;   // 2^18 float4 per 1M-elem matrix
__global__ __launch_bounds__(256) void k_convert_all(
        const float4* __restrict__ Wq, const float4* __restrict__ Wk,
        const float4* __restrict__ Wv, const float4* __restrict__ Ws,
        const float4* __restrict__ Wo, const float4* __restrict__ Wh,
        const float4* __restrict__ Wp1, const float4* __restrict__ Wp2,
        const float4* __restrict__ x, uint4* __restrict__ arena,
        uint4* __restrict__ xb, float4* __restrict__ wz) {
    int i = blockIdx.x * 256 + threadIdx.x;
    int stride = gridDim.x * 256;
    for (int i2 = i; i2 < (CB * CH * CS) / 4; i2 += stride)
        wz[i2] = (float4){0.f, 0.f, 0.f, 0.f};
    for (; i < 9 * Q4; i += stride) {
        const int F = i * 2;               // float4 index
        const int seg = F >> 18;           // Q4 = 2^18
        const float4* src; int off;
        if (seg < 6) {
            src = (seg == 0) ? Wq : (seg == 1) ? Wk : (seg == 2) ? Wv
                : (seg == 3) ? Ws : (seg == 4) ? Wo : Wh;
            off = F & (Q4 - 1);
        } else if (seg < 10) { src = Wp1; off = F - 6 * Q4; }
        else if (seg < 14)   { src = Wp2; off = F - 10 * Q4; }
        else                 { src = x;   off = F - 14 * Q4; }
        float4 a = src[off], b = src[off + 1];
        uint4 o;
        o.x = (unsigned)f2bf(a.x) | ((unsigned)f2bf(a.y) << 16);
        o.y = (unsigned)f2bf(a.z) | ((unsigned)f2bf(a.w) << 16);
        o.z = (unsigned)f2bf(b.x) | ((unsigned)f2bf(b.y) << 16);
        o.w = (unsigned)f2bf(b.z) | ((unsigned)f2bf(b.w) << 16);
        if (seg < 14) arena[i] = o;
        else          xb[i - 7 * Q4] = o;
    }
}

// ---------------- bf16 MFMA GEMM: C[M,N] = A[M,K]*B[N,K]^T ----------------
// BK=64, XOR-swizzled LDS staging (conflict-free gll16 writes AND b128 frag reads).
// Epilogue: LDS-staged transpose -> full-line global_store_dwordx4.
// EPI 0: bf16 partial out (split-K slices stacked at z*M*N, summed in LN).
// EPI 3: +bias relu bf16 out. EPI 4: QKVS fused per-head-LN epilogue.
template <int TN, int EPI, int SPLITK>
__global__ __launch_bounds__(256, 4) void k_gemm_bt(
        const ush* __restrict__ A, const ush* __restrict__ Bm,
        ush* __restrict__ Cb,
        const float* __restrict__ bias, const float* __restrict__ bias2,
        ush* __restrict__ out2, ush* __restrict__ out3, ush* __restrict__ sb,
        int N, int K) {
    constexpr int NJ  = TN / 32;
    constexpr int BCH = TN / 32;
    constexpr int EPS = TN + 8;
    constexpr int STG = (128 + TN) * 64;
    constexpr int LDS_USH = (STG > 128 * EPS) ? STG : 128 * EPS;
    __shared__ ush smem[LDS_USH];
    ush* As = smem;
    ush* Bs = smem + 128 * 64;
    ush* Cs = smem;

    const int tid  = threadIdx.x;
    const int wave = tid >> 6, lane = tid & 63;
    const int quad = lane >> 4, r = lane & 15;
    const int wm = wave >> 1, wn = wave & 1;
    const int bm = blockIdx.x, bn = blockIdx.y;

    const int kcnt  = K / SPLITK;
    const int kbase = blockIdx.z * kcnt;
    ush* dst0 = Cb;
    if (SPLITK > 1) dst0 += (size_t)blockIdx.z * (size_t)gridDim.x * 128 * N;

    const int trow = tid >> 3, tk8 = tid & 7;
    const int kcl  = tk8 ^ (trow & 7);
    const ush* ap = A  + (size_t)(bm * 128 + trow) * K + kbase + kcl * 8;
    const ush* bp = Bm + (size_t)(bn * TN  + trow) * K + kbase + kcl * 8;
    ush* asd = As + tid * 8;
    ush* bsd = Bs + tid * 8;
    const size_t cstep = (size_t)32 * K;

    f32x4 acc[4][NJ];
#pragma unroll
    for (int i = 0; i < 4; i++)
#pragma unroll
        for (int j = 0; j < NJ; j++) acc[i][j] = (f32x4){0.f, 0.f, 0.f, 0.f};

    const int rx = r & 7;
    for (int k0 = 0; k0 < kcnt; k0 += 64) {
#pragma unroll
        for (int c = 0; c < 4; c++)   gll16(ap + c * cstep, asd + c * 2048);
#pragma unroll
        for (int c = 0; c < BCH; c++) gll16(bp + c * cstep, bsd + c * 2048);
        ap += 64; bp += 64;
        __syncthreads();
#pragma unroll
        for (int h = 0; h < 2; h++) {
            const int kx = (((h << 2) | quad) ^ rx) * 8;
            bf16x8 af[4], bfv[NJ];
#pragma unroll
            for (int i = 0; i < 4; i++)
                af[i] = *(const bf16x8*)(As + (wm * 64 + i * 16 + r) * 64 + kx);
#pragma unroll
            for (int j = 0; j < NJ; j++)
                bfv[j] = *(const bf16x8*)(Bs + (wn * (TN / 2) + j * 16 + r) * 64 + kx);
#pragma unroll
            for (int i = 0; i < 4; i++)
#pragma unroll
                for (int j = 0; j < NJ; j++)
                    acc[i][j] = __builtin_amdgcn_mfma_f32_16x16x32_bf16(af[i], bfv[j], acc[i][j], 0, 0, 0);
        }
        __syncthreads();
    }

    // ---- deposit output tile into LDS (bf16, padded rows) ----
    if (EPI == 4 && bn < 24) {
        float g4[4], b4[4];
#pragma unroll
        for (int j = 0; j < 4; j++) { g4[j] = bias[j * 16 + r]; b4[j] = bias2[j * 16 + r]; }
#pragma unroll
        for (int i = 0; i < 4; i++) {
            const int row = wm * 64 + i * 16 + quad * 4;
#pragma unroll
            for (int g = 0; g < 4; g++) {
                float s = 0.f, q = 0.f;
#pragma unroll
                for (int j = 0; j < 4; j++) { float v = acc[i][j][g]; s += v; q += v * v; }
                s += __shfl_xor(s, 1); q += __shfl_xor(q, 1);
                s += __shfl_xor(s, 2); q += __shfl_xor(q, 2);
                s += __shfl_xor(s, 4); q += __shfl_xor(q, 4);
                s += __shfl_xor(s, 8); q += __shfl_xor(q, 8);
                float mu   = s * (1.f / 64.f);
                float rstd = rsqrtf(q * (1.f / 64.f) - mu * mu + 1e-5f);
#pragma unroll
                for (int j = 0; j < 4; j++) {
                    float y = (acc[i][j][g] - mu) * rstd * g4[j] + b4[j];
                    Cs[(row + g) * EPS + wn * 64 + j * 16 + r] = f2bf(y);
                }
            }
        }
    } else {
#pragma unroll
        for (int i = 0; i < 4; i++) {
            const int row = wm * 64 + i * 16 + quad * 4;
#pragma unroll
            for (int j = 0; j < NJ; j++) {
                const int col = wn * (TN / 2) + j * 16 + r;
                float bv = (EPI == 3) ? bias[bn * TN + col] : 0.f;
#pragma unroll
                for (int g = 0; g < 4; g++) {
                    float v = acc[i][j][g] + bv;
                    if (EPI == 3) v = fmaxf(v, 0.f);
                    Cs[(row + g) * EPS + col] = f2bf(v);
                }
            }
        }
    }
    __syncthreads();

    // ---- vectorized store: full 128B-line coverage ----
    ush* dst = dst0;
    int colbase = bn * TN, Nn = N;
    if (EPI == 4) {
        Nn = 1024;
        if (bn < 8)       { dst = Cb;   colbase = bn * 128; }
        else if (bn < 16) { dst = out2; colbase = (bn - 8) * 128; }
        else if (bn < 24) { dst = out3; colbase = (bn - 16) * 128; }
        else              { dst = sb;   colbase = (bn - 24) * 128; }
    }
    const int tpr = TN / 8;
    const int rpp = 2048 / TN;
    const int srow2 = tid / tpr;
    const int scol2 = (tid % tpr) * 8;
#pragma unroll
    for (int pp = 0; pp < TN / 16; pp++) {
        const int rr = pp * rpp + srow2;
        uint4 vv = *(const uint4*)&Cs[rr * EPS + scol2];
        *(uint4*)&dst[(size_t)(bm * 128 + rr) * Nn + colbase + scol2] = vv;
    }
}

// ---------------- banded attention column-sum kernel ----------------
// wcol[b,h,l] = sum_q softmax_row_q(pre)[l]; exp(pre-8)==0 in fp32 for |q-l|>~104,
// so 3 K-tiles of 64 suffice. All-masked row q=0 adds uniform 1/1024 in k_scale_v.
__global__ __launch_bounds__(256) void k_attn(const ush* __restrict__ qb,
                                              const ush* __restrict__ kb,
                                              const float* __restrict__ mask,
                                              float* __restrict__ wcol) {
    __shared__ ush   Qs[64][72];
    __shared__ ush   Ks[64][72];
    __shared__ float colpart[4][64];

    const int tid  = threadIdx.x;
    const int wave = tid >> 6, lane = tid & 63;
    const int quad = lane >> 4, r = lane & 15;
    const int bh = blockIdx.x, bi = bh >> 4, hi = bh & 15;
    const int q0 = blockIdx.y * 64;

    {
        int row = tid >> 2, seg = (tid & 3) * 16;
        const ush* src = qb + ((size_t)(bi * CS + q0 + row) * CD + hi * 64 + seg);
        *(uint4*)&Qs[row][seg]     = *(const uint4*)src;
        *(uint4*)&Qs[row][seg + 8] = *(const uint4*)(src + 8);
    }
    __syncthreads();
    bf16x8 af0 = *(const bf16x8*)&Qs[wave * 16 + r][quad * 8];
    bf16x8 af1 = *(const bf16x8*)&Qs[wave * 16 + r][32 + quad * 8];

    float mq[4];
#pragma unroll
    for (int g = 0; g < 4; g++) mq[g] = mask[bi * CS + q0 + wave * 16 + quad * 4 + g];

    const int t0 = (q0 >= 128) ? 0 : ((q0 >= 64) ? 1 : 2);
    float pr[3][4][4];
    float s_loc[4] = {0.f, 0.f, 0.f, 0.f};

    for (int t = t0; t < 3; t++) {
        const int l0 = q0 - 128 + t * 64;
        __syncthreads();
        {
            int row = tid >> 2, seg = (tid & 3) * 16;
            const ush* src = kb + ((size_t)(bi * CS + l0 + row) * CD + hi * 64 + seg);
            *(uint4*)&Ks[row][seg]     = *(const uint4*)src;
            *(uint4*)&Ks[row][seg + 8] = *(const uint4*)(src + 8);
        }
        __syncthreads();
#pragma unroll
        for (int jt = 0; jt < 4; jt++) {
            bf16x8 bf0 = *(const bf16x8*)&Ks[jt * 16 + r][quad * 8];
            bf16x8 bf1 = *(const bf16x8*)&Ks[jt * 16 + r][32 + quad * 8];
            f32x4 sc = (f32x4){0.f, 0.f, 0.f, 0.f};
            sc = __builtin_amdgcn_mfma_f32_16x16x32_bf16(af0, bf0, sc, 0, 0, 0);
            sc = __builtin_amdgcn_mfma_f32_16x16x32_bf16(af1, bf1, sc, 0, 0, 0);
            const int l = l0 + jt * 16 + r;
            const float ml = mask[bi * CS + l];
#pragma unroll
            for (int g = 0; g < 4; g++) {
                const int qg = q0 + wave * 16 + quad * 4 + g;
                float e  = sc[g] * 0.03125f;
                float mv = (qg > l) ? 0.f : mq[g] * ml * (-1e20f);
                float p  = __expf(e + mv - fabsf((float)(qg - l)) - 8.f);
                pr[t][jt][g] = p;
                s_loc[g] += p;
            }
        }
    }

    float rs[4];
#pragma unroll
    for (int g = 0; g < 4; g++) {
        float s = s_loc[g];
        s += __shfl_xor(s, 1); s += __shfl_xor(s, 2);
        s += __shfl_xor(s, 4); s += __shfl_xor(s, 8);
        rs[g] = (s > 0.f) ? 1.f / s : 0.f;
    }

    for (int t = t0; t < 3; t++) {
        const int l0 = q0 - 128 + t * 64;
#pragma unroll
        for (int jt = 0; jt < 4; jt++) {
            float csum = 0.f;
#pragma unroll
            for (int g = 0; g < 4; g++) csum += pr[t][jt][g] * rs[g];
            csum += __shfl_xor(csum, 16);
            csum += __shfl_xor(csum, 32);
            if (quad == 0) colpart[wave][jt * 16 + r] = csum;
        }
        __syncthreads();
        if (tid < 64) {
            float v = colpart[0][tid] + colpart[1][tid] + colpart[2][tid] + colpart[3][tid];
            atomicAdd(&wcol[(size_t)bh * CS + l0 + tid], v);
        }
        __syncthreads();
    }
}

// ---------------- scale v by column weights (+ uniform row-0 term), 8 elems/thread ----
__global__ __launch_bounds__(256) void k_scale_v(const ush* __restrict__ vb,
                                                 const float* __restrict__ wcol,
                                                 ush* __restrict__ out) {
    const int g = blockIdx.x * 256 + threadIdx.x;   // group of 8 elems
    const int token = g >> 7;
    const int cg = g & 127;
    const int c0 = cg * 8, h = cg >> 3;
    const int l = token & (CS - 1), b = token >> 10;
    const float w = wcol[(size_t)(b * CH + h) * CS + l] + (1.f / 1024.f);
    float d[8];
    ub8(*(const uint4*)&vb[(size_t)token * CD + c0], d);
#pragma unroll
    for (int j = 0; j < 8; j++) d[j] *= w;
    *(uint4*)&out[(size_t)token * CD + c0] = pb8(d);
}

// ---------------- row layernorm over D=1024 (bf16 in, 16B/lane), fused variants ----
// MODE 0: LN(b0+b1+badd) -> bf16                        (Wo partials + bo)
// MODE 2: sf=LN(b0); hf=LN(b1+b2); f=sigmoid(sf+hf+badd); LN(f*sf+(1-f)*hf) -> bf16
// MODE 3: LN(b0+b1+b2+badd) -> f32                      (FFN2 partials + g + bp2)
__device__ __forceinline__ void stats128(float s, float q, float* red,
                                         int wave, int lane, float& mu, float& rstd) {
#pragma unroll
    for (int off = 32; off >= 1; off >>= 1) {
        s += __shfl_xor(s, off);
        q += __shfl_xor(q, off);
    }
    if (lane == 0) { red[wave] = s; red[2 + wave] = q; }
    __syncthreads();
    s = red[0] + red[1];
    q = red[2] + red[3];
    mu = s * (1.f / 1024.f);
    rstd = rsqrtf(q * (1.f / 1024.f) - mu * mu + 1e-5f);
    __syncthreads();
}

template <int MODE>
__global__ __launch_bounds__(128) void k_ln_row(const ush* __restrict__ b0,
                                                const ush* __restrict__ b1,
                                                const ush* __restrict__ b2,
                                                const float* __restrict__ badd,
                                                const float* __restrict__ gam,
                                                const float* __restrict__ bet,
                                                float* __restrict__ outf,
                                                ush* __restrict__ outb) {
    __shared__ float red[4];
    const int tid = threadIdx.x, wave = tid >> 6, lane = tid & 63;
    const size_t base = (size_t)blockIdx.x * CD;
    const int c0 = tid * 8;
    float t[8], sr[8], tmp[8], gv[8], bv[8];
    float s = 0.f, q = 0.f, mu, rstd;

    *(float4*)&gv[0] = *(const float4*)&gam[c0];
    *(float4*)&gv[4] = *(const float4*)&gam[c0 + 4];
    *(float4*)&bv[0] = *(const float4*)&bet[c0];
    *(float4*)&bv[4] = *(const float4*)&bet[c0 + 4];

    if (MODE == 2) {
        float av[8];
        *(float4*)&av[0] = *(const float4*)&badd[c0];
        *(float4*)&av[4] = *(const float4*)&badd[c0 + 4];
        ub8(*(const uint4*)&b0[base + c0], sr);
        ub8(*(const uint4*)&b1[base + c0], t);
        ub8(*(const uint4*)&b2[base + c0], tmp);
#pragma unroll
        for (int j = 0; j < 8; j++) t[j] += tmp[j];
#pragma unroll
        for (int j = 0; j < 8; j++) { s += sr[j]; q += sr[j] * sr[j]; }
        stats128(s, q, red, wave, lane, mu, rstd);
#pragma unroll
        for (int j = 0; j < 8; j++) sr[j] = (sr[j] - mu) * rstd * gv[j] + bv[j];  // s_f
        s = 0.f; q = 0.f;
#pragma unroll
        for (int j = 0; j < 8; j++) { s += t[j]; q += t[j] * t[j]; }
        stats128(s, q, red, wave, lane, mu, rstd);
#pragma unroll
        for (int j = 0; j < 8; j++) {
            float hf = (t[j] - mu) * rstd * gv[j] + bv[j];
            float f  = 1.f / (1.f + __expf(-(sr[j] + hf + av[j])));
            t[j] = f * sr[j] + (1.f - f) * hf;
        }
    } else {
        float av[8];
        *(float4*)&av[0] = *(const float4*)&badd[c0];
        *(float4*)&av[4] = *(const float4*)&badd[c0 + 4];
        ub8(*(const uint4*)&b0[base + c0], t);
        ub8(*(const uint4*)&b1[base + c0], tmp);
#pragma unroll
        for (int j = 0; j < 8; j++) t[j] += tmp[j] + av[j];
        if (MODE == 3) {
            ub8(*(const uint4*)&b2[base + c0], tmp);
#pragma unroll
            for (int j = 0; j < 8; j++) t[j] += tmp[j];
        }
    }

    s = 0.f; q = 0.f;
#pragma unroll
    for (int j = 0; j < 8; j++) { s += t[j]; q += t[j] * t[j]; }
    stats128(s, q, red, wave, lane, mu, rstd);

    float y[8];
#pragma unroll
    for (int j = 0; j < 8; j++) y[j] = (t[j] - mu) * rstd * gv[j] + bv[j];
    if (MODE == 3) {
        *(float4*)&outf[base + c0]     = *(float4*)&y[0];
        *(float4*)&outf[base + c0 + 4] = *(float4*)&y[4];
    } else {
        *(uint4*)&outb[base + c0] = pb8(y);
    }
}

// ---------------- host launch ----------------
extern "C" void kernel_launch(void* const* d_in, const int* in_sizes, int n_in,
                              void* d_out, int out_size, void* d_ws, size_t ws_size,
                              hipStream_t stream) {
    const float* x    = (const float*)d_in[0];
    const float* mask = (const float*)d_in[1];
    const float* Wq   = (const float*)d_in[2];
    const float* Wk   = (const float*)d_in[3];
    const float* Wv   = (const float*)d_in[4];
    const float* ln1g = (const float*)d_in[5];
    const float* ln1b = (const float*)d_in[6];
    const float* Wo   = (const float*)d_in[7];
    const float* bo   = (const float*)d_in[8];
    const float* ln2g = (const float*)d_in[9];
    const float* ln2b = (const float*)d_in[10];
    const float* Ws   = (const float*)d_in[11];
    const float* Wh   = (const float*)d_in[12];
    const float* bf_  = (const float*)d_in[13];
    const float* lnfgg = (const float*)d_in[14];
    const float* lnfgb = (const float*)d_in[15];
    const float* Wp1  = (const float*)d_in[16];
    const float* bp1  = (const float*)d_in[17];
    const float* Wp2  = (const float*)d_in[18];
    const float* bp2  = (const float*)d_in[19];
    const float* lnffg = (const float*)d_in[20];
    const float* lnffb = (const float*)d_in[21];
    float* out = (float*)d_out;

    char* p = (char*)d_ws;
    auto alloc = [&](size_t bytes) -> char* {
        char* r = p;
        p += (bytes + 255) & ~(size_t)255;
        return r;
    };
    ush*   arena = (ush*)alloc((size_t)14 * CD * CD * 2);  // 28 MB
    ush*   Wob   = arena + (size_t)4 * CD * CD;
    ush*   Whb   = arena + (size_t)5 * CD * CD;
    ush*   Wp1b  = arena + (size_t)6 * CD * CD;
    ush*   Wp2b  = arena + (size_t)10 * CD * CD;
    ush*   xb    = (ush*)alloc((size_t)CNT * CD * 2);      // 8 MB
    ush*   klnb  = (ush*)alloc((size_t)CNT * CD * 2);      // 8 MB (hb alias)
    ush*   vb    = (ush*)alloc((size_t)CNT * CD * 2);      // 8 MB
    ush*   qlnb  = (ush*)alloc((size_t)CNT * CD * 2);      // 8 MB (attb alias)
    ush*   gb    = (ush*)alloc((size_t)CNT * CD * 2);      // 8 MB
    ush*   P     = (ush*)alloc((size_t)2 * CNT * CD * 2);  // 16 MB split-K bf16 partials
    ush*   P1    = P + (size_t)CNT * CD;
    ush*   ff1b  = (ush*)alloc((size_t)CNT * CDFF * 2);    // 32 MB (sbuf aliases front)
    float* wcol  = (float*)alloc((size_t)CB * CH * CS * 4);
    ush*   sbuf  = ff1b;           // s raw bf16; consumed by gate LN before FFN1 writes
    ush*   attb  = qlnb;           // q-ln consumed by k_attn before k_scale_v writes
    ush*   hb    = klnb;           // k-ln consumed by k_attn before ln_row<0> writes

    dim3 blk(256);

    k_convert_all<<<dim3(4608), blk, 0, stream>>>(
        (const float4*)Wq, (const float4*)Wk, (const float4*)Wv, (const float4*)Ws,
        (const float4*)Wo, (const float4*)Wh, (const float4*)Wp1, (const float4*)Wp2,
        (const float4*)x, (uint4*)arena, (uint4*)xb, (float4*)wcol);

    // fused QKVS projection: q,k,v per-head-LN -> bf16; s raw -> bf16
    k_gemm_bt<128, 4, 1><<<dim3(32, 32, 1), blk, 0, stream>>>(
        xb, arena, qlnb, ln1g, ln1b, klnb, vb, sbuf, 4096, CD);

    // attention column sums (banded)
    k_attn<<<dim3(CB * CH, CS / 64), blk, 0, stream>>>(qlnb, klnb, mask, wcol);
    k_scale_v<<<dim3(CNT * CD / 8 / 256), blk, 0, stream>>>(vb, wcol, attb);

    // output projection (split-K=2 bf16 partials) + LN2 (+bo)
    k_gemm_bt<64, 0, 2><<<dim3(32, 16, 2), blk, 0, stream>>>(
        attb, Wob, P, nullptr, nullptr, nullptr, nullptr, nullptr, CD, CD);
    k_ln_row<0><<<dim3(CNT), dim3(128), 0, stream>>>(P, P1, nullptr, bo, ln2g, ln2b, nullptr, hb);

    // h_f path + gate (s_f LN fused here)
    k_gemm_bt<64, 0, 2><<<dim3(32, 16, 2), blk, 0, stream>>>(
        hb, Whb, P, nullptr, nullptr, nullptr, nullptr, nullptr, CD, CD);
    k_ln_row<2><<<dim3(CNT), dim3(128), 0, stream>>>(sbuf, P, P1, bf_, lnfgg, lnfgb, nullptr, gb);

    // FFN + residual (g as bf16) + final LN (+bp2)
    k_gemm_bt<128, 3, 1><<<dim3(32, 32, 1), blk, 0, stream>>>(
        gb, Wp1b, ff1b, bp1, nullptr, nullptr, nullptr, nullptr, CDFF, CD);
    k_gemm_bt<64, 0, 2><<<dim3(32, 16, 2), blk, 0, stream>>>(
        ff1b, Wp2b, P, nullptr, nullptr, nullptr, nullptr, nullptr, CD, CDFF);
    k_ln_row<3><<<dim3(CNT), dim3(128), 0, stream>>>(P, P1, gb, bp2, lnffg, lnffb, out, nullptr);

    (void)in_sizes; (void)n_in; (void)out_size; (void)ws_size;
}